// Round 1
// baseline (1367.108 us; speedup 1.0000x reference)
//
#include <hip/hip_runtime.h>
#include <hip/hip_bf16.h>

typedef unsigned short u16;
typedef __bf16 bf16x8 __attribute__((ext_vector_type(8)));
typedef float f32x4 __attribute__((ext_vector_type(4)));

#define DI __device__ __forceinline__

DI u16 f2b(float f) {
  unsigned u = __builtin_bit_cast(unsigned, f);
  unsigned r = (u + 0x7FFFu + ((u >> 16) & 1u)) >> 16;
  return (u16)r;
}
DI float b2f(u16 h) {
  unsigned u = ((unsigned)h) << 16;
  return __builtin_bit_cast(float, u);
}
DI float wave_sum(float v) {
#pragma unroll
  for (int o = 32; o > 0; o >>= 1) v += __shfl_down(v, o);
  return v;
}
DI float wave_max(float v) {
#pragma unroll
  for (int o = 32; o > 0; o >>= 1) v = fmaxf(v, __shfl_down(v, o));
  return v;
}
DI float gelu_tanh(float v) {
  float u = 0.7978845608028654f * (v + 0.044715f * v * v * v);
  float eu = __expf(-2.0f * fabsf(u));
  float th = (1.0f - eu) / (1.0f + eu);
  th = (u < 0.0f) ? -th : th;
  return 0.5f * v * (1.0f + th);
}

// ---------------------------------------------------------------------------
// GEMM core: C[64m x 64n] += A[M,K](bf16) x B^T, 4 waves, each wave = 16 rows
// x 64 cols via 4x mfma_f32_16x16x32_bf16. LDS row stride 40 u16 (80B: 16B
// aligned, 2-way bank alias only).
// TRANSB=false: B is Bt[N,K] row-major. TRANSB=true: B is [K,N] row-major,
// transposed while staging to LDS.
// ---------------------------------------------------------------------------
template <bool GATHER, bool TRANSB>
DI void gemm_core(const u16* __restrict__ A, int lda, const u16* __restrict__ B,
                  int ldb, int K, int M_rem, int N_rem,
                  const int* __restrict__ rmap, u16* As, u16* Bs, f32x4 acc[4]) {
  const int t = threadIdx.x;
  const int lane = t & 63, wave = t >> 6;
  const int fr = lane & 15;            // fragment row (m or n within 16)
  const int fko = (lane >> 4) << 3;    // fragment k offset (0,8,16,24)
  const int lr = t >> 2;               // staging row 0..63
  const int lc = (t & 3) << 3;         // staging k chunk 0/8/16/24
  const int bkr = t >> 3;              // TRANSB: k row 0..31
  const int bnc = (t & 7) << 3;        // TRANSB: n chunk 0..56

  int grow = 0;
  bool arow_ok = (lr < M_rem);
  if (arow_ok) grow = GATHER ? rmap[lr] : lr;

  for (int kb = 0; kb < K; kb += 32) {
    uint4 av = {0u, 0u, 0u, 0u};
    if (arow_ok) av = *(const uint4*)(A + (size_t)grow * lda + (kb + lc));
    *(uint4*)(As + lr * 40 + lc) = av;
    if (!TRANSB) {
      uint4 bv = {0u, 0u, 0u, 0u};
      if (lr < N_rem) bv = *(const uint4*)(B + (size_t)lr * ldb + (kb + lc));
      *(uint4*)(Bs + lr * 40 + lc) = bv;
    } else {
      uint4 bv = *(const uint4*)(B + (size_t)(kb + bkr) * ldb + bnc);
      const u16* pv = (const u16*)&bv;
#pragma unroll
      for (int j = 0; j < 8; ++j) Bs[(bnc + j) * 40 + bkr] = pv[j];
    }
    __syncthreads();
    bf16x8 af = *(const bf16x8*)(As + ((wave << 4) + fr) * 40 + fko);
#pragma unroll
    for (int nt = 0; nt < 4; ++nt) {
      bf16x8 bfr = *(const bf16x8*)(Bs + ((nt << 4) + fr) * 40 + fko);
      acc[nt] = __builtin_amdgcn_mfma_f32_16x16x32_bf16(af, bfr, acc[nt], 0, 0, 0);
    }
    __syncthreads();
  }
}

constexpr int EP_BF16 = 0;
constexpr int EP_F32RES = 1;

// Generic batched GEMM. z decomposes as (zb = z/Zh, zh = z%Zh) with separate
// strides, covering plain GEMM (Zh=1, strides 0) and per-(batch,head) GEMMs.
template <int EP, bool TRANSB>
__global__ __launch_bounds__(256) void gemm_bt_k(
    const u16* __restrict__ A, int lda, const u16* __restrict__ B, int ldb,
    const float* __restrict__ bias, float* __restrict__ Cf, u16* __restrict__ Cb,
    int ldc, const float* __restrict__ resid, int M, int N, int K, float alpha,
    int Zh, long sAb, long sAh, long sBb, long sBh, long sCb, long sCh) {
  __shared__ __align__(16) u16 As[64 * 40];
  __shared__ __align__(16) u16 Bs[64 * 40];
  const int z = blockIdx.z;
  const int zb = z / Zh, zh = z - zb * Zh;
  const u16* Ap = A + zb * sAb + zh * sAh;
  const u16* Bp = B + zb * sBb + zh * sBh;
  const long coff = zb * sCb + zh * sCh;
  const int m_base = blockIdx.y << 6, n_base = blockIdx.x << 6;
  const int M_rem = min(64, M - m_base);
  const int N_rem = min(64, N - n_base);
  Ap += (size_t)m_base * lda;
  Bp += TRANSB ? (size_t)n_base : (size_t)n_base * ldb;
  f32x4 acc[4];
  const f32x4 z4 = {0.f, 0.f, 0.f, 0.f};
#pragma unroll
  for (int i = 0; i < 4; ++i) acc[i] = z4;
  gemm_core<false, TRANSB>(Ap, lda, Bp, ldb, K, M_rem, N_rem, nullptr, As, Bs, acc);
  const int lane = threadIdx.x & 63, wave = threadIdx.x >> 6;
  const int r0 = (wave << 4) + ((lane >> 4) << 2);
  const int c0 = lane & 15;
#pragma unroll
  for (int nt = 0; nt < 4; ++nt) {
    const int n = n_base + (nt << 4) + c0;
    if (n >= N) continue;
    const float bv = bias ? bias[n] : 0.0f;
#pragma unroll
    for (int r = 0; r < 4; ++r) {
      const int ml = r0 + r;
      if (ml >= M_rem) continue;
      const size_t m = (size_t)(m_base + ml);
      float v = acc[nt][r] * alpha + bv;
      if (EP == EP_F32RES)
        Cf[(size_t)coff + m * ldc + n] = v + resid[m * ldc + n];
      else
        Cb[(size_t)coff + m * ldc + n] = f2b(v);
    }
  }
}

// Expert GEMM1: gathered tokens x W1t[e], gelu epilogue -> H1 slots (bf16)
__global__ __launch_bounds__(256) void moe_gemm1_k(
    const u16* __restrict__ X, const u16* __restrict__ W1t,
    const float* __restrict__ b1, const int* __restrict__ counts,
    const int* __restrict__ offs, const int* __restrict__ token_ids,
    u16* __restrict__ H1) {
  __shared__ __align__(16) u16 As[64 * 40];
  __shared__ __align__(16) u16 Bs[64 * 40];
  const int e = blockIdx.z;
  const int Me = counts[e];
  const int m_base = blockIdx.y << 6;
  if (m_base >= Me) return;
  const int n_base = blockIdx.x << 6;
  const int M_rem = min(64, Me - m_base);
  const int off_e = offs[e];
  const int* rmap = token_ids + off_e + m_base;
  const u16* B = W1t + (size_t)e * 4096 * 1024 + (size_t)n_base * 1024;
  f32x4 acc[4];
  const f32x4 z4 = {0.f, 0.f, 0.f, 0.f};
#pragma unroll
  for (int i = 0; i < 4; ++i) acc[i] = z4;
  gemm_core<true, false>(X, 1024, B, 1024, 1024, M_rem, 64, rmap, As, Bs, acc);
  const int lane = threadIdx.x & 63, wave = threadIdx.x >> 6;
  const int r0 = (wave << 4) + ((lane >> 4) << 2);
  const int c0 = lane & 15;
  const float* b1e = b1 + (size_t)e * 4096;
#pragma unroll
  for (int nt = 0; nt < 4; ++nt) {
    const int n = n_base + (nt << 4) + c0;
    const float bv = b1e[n];
#pragma unroll
    for (int r = 0; r < 4; ++r) {
      const int ml = r0 + r;
      if (ml >= M_rem) continue;
      float v = acc[nt][r] + bv;
      H1[(size_t)(off_e + m_base + ml) * 4096 + n] = f2b(gelu_tanh(v));
    }
  }
}

// Expert GEMM2: H1 slots x W2t[e], gate-weighted atomic scatter into out
__global__ __launch_bounds__(256) void moe_gemm2_k(
    const u16* __restrict__ H1, const u16* __restrict__ W2t,
    const int* __restrict__ counts, const int* __restrict__ offs,
    const int* __restrict__ token_ids, const float* __restrict__ tok_gate,
    float* __restrict__ Out) {
  __shared__ __align__(16) u16 As[64 * 40];
  __shared__ __align__(16) u16 Bs[64 * 40];
  const int e = blockIdx.z;
  const int Me = counts[e];
  const int m_base = blockIdx.y << 6;
  if (m_base >= Me) return;
  const int n_base = blockIdx.x << 6;
  const int M_rem = min(64, Me - m_base);
  const int off_e = offs[e];
  const u16* A = H1 + (size_t)(off_e + m_base) * 4096;
  const u16* B = W2t + (size_t)e * 1024 * 4096 + (size_t)n_base * 4096;
  f32x4 acc[4];
  const f32x4 z4 = {0.f, 0.f, 0.f, 0.f};
#pragma unroll
  for (int i = 0; i < 4; ++i) acc[i] = z4;
  gemm_core<false, false>(A, 4096, B, 4096, 4096, M_rem, 64, nullptr, As, Bs, acc);
  const int lane = threadIdx.x & 63, wave = threadIdx.x >> 6;
  const int r0 = (wave << 4) + ((lane >> 4) << 2);
  const int c0 = lane & 15;
#pragma unroll
  for (int r = 0; r < 4; ++r) {
    const int ml = r0 + r;
    if (ml >= M_rem) continue;
    const int slot = off_e + m_base + ml;
    const int tok = token_ids[slot];
    const float gt = tok_gate[slot];
#pragma unroll
    for (int nt = 0; nt < 4; ++nt) {
      const int n = n_base + (nt << 4) + c0;
      atomicAdd(Out + (size_t)tok * 1024 + n, gt * acc[nt][r]);
    }
  }
}

// LayerNorm over 1024 cols, writes bf16 (+ optional per-row stats for gating)
__global__ __launch_bounds__(256) void ln_k(const float* __restrict__ X,
                                            const float* __restrict__ g,
                                            const float* __restrict__ b,
                                            u16* __restrict__ Y,
                                            float2* __restrict__ stats) {
  const int row = blockIdx.x;
  const float4 xv = ((const float4*)(X + (size_t)row * 1024))[threadIdx.x];
  float s = xv.x + xv.y + xv.z + xv.w;
  float s2 = xv.x * xv.x + xv.y * xv.y + xv.z * xv.z + xv.w * xv.w;
  s = wave_sum(s);
  s2 = wave_sum(s2);
  __shared__ float rs_[4], r2_[4];
  const int lane = threadIdx.x & 63, wave = threadIdx.x >> 6;
  if (lane == 0) { rs_[wave] = s; r2_[wave] = s2; }
  __syncthreads();
  const float tot = rs_[0] + rs_[1] + rs_[2] + rs_[3];
  const float tot2 = r2_[0] + r2_[1] + r2_[2] + r2_[3];
  const float mu = tot * (1.0f / 1024.0f);
  const float var = tot2 * (1.0f / 1024.0f) - mu * mu;
  const float rstd = rsqrtf(var + 1e-5f);
  const float4 gv = ((const float4*)g)[threadIdx.x];
  const float4 bv = ((const float4*)b)[threadIdx.x];
  ushort4 o;
  o.x = f2b((xv.x - mu) * rstd * gv.x + bv.x);
  o.y = f2b((xv.y - mu) * rstd * gv.y + bv.y);
  o.z = f2b((xv.z - mu) * rstd * gv.z + bv.z);
  o.w = f2b((xv.w - mu) * rstd * gv.w + bv.w);
  ((ushort4*)(Y + (size_t)row * 1024))[threadIdx.x] = o;
  if (stats != nullptr && threadIdx.x == 0) stats[row] = make_float2(mu, rstd);
}

// Softmax over 2048-wide bf16 rows, in place
__global__ __launch_bounds__(256) void softmax_k(u16* __restrict__ P) {
  uint4* row = (uint4*)(P + (size_t)blockIdx.x * 2048);
  uint4 raw = row[threadIdx.x];
  u16* us = (u16*)&raw;
  float f[8];
  float mx = -1e30f;
#pragma unroll
  for (int j = 0; j < 8; ++j) {
    f[j] = b2f(us[j]);
    mx = fmaxf(mx, f[j]);
  }
  mx = wave_max(mx);
  __shared__ float redm[4], redsum[4];
  const int lane = threadIdx.x & 63, wave = threadIdx.x >> 6;
  if (lane == 0) redm[wave] = mx;
  __syncthreads();
  mx = fmaxf(fmaxf(redm[0], redm[1]), fmaxf(redm[2], redm[3]));
  float sum = 0.0f;
#pragma unroll
  for (int j = 0; j < 8; ++j) {
    f[j] = __expf(f[j] - mx);
    sum += f[j];
  }
  sum = wave_sum(sum);
  if (lane == 0) redsum[wave] = sum;
  __syncthreads();
  sum = redsum[0] + redsum[1] + redsum[2] + redsum[3];
  const float inv = 1.0f / sum;
#pragma unroll
  for (int j = 0; j < 8; ++j) us[j] = f2b(f[j] * inv);
  row[threadIdx.x] = raw;
}

// Gating logits in fp32 (LN recomputed exactly from stats: avoids bf16 top-2 flips)
__global__ __launch_bounds__(256) void logits_k(
    const float* __restrict__ X2, const float2* __restrict__ stats,
    const float* __restrict__ g, const float* __restrict__ b,
    const float* __restrict__ Wg, float* __restrict__ logits) {
  const int row = blockIdx.x;
  const float2 st = stats[row];
  const float4 xv = ((const float4*)(X2 + (size_t)row * 1024))[threadIdx.x];
  const float4 gv = ((const float4*)g)[threadIdx.x];
  const float4 bv = ((const float4*)b)[threadIdx.x];
  float xt[4];
  xt[0] = (xv.x - st.x) * st.y * gv.x + bv.x;
  xt[1] = (xv.y - st.x) * st.y * gv.y + bv.y;
  xt[2] = (xv.z - st.x) * st.y * gv.z + bv.z;
  xt[3] = (xv.w - st.x) * st.y * gv.w + bv.w;
  float acc[8] = {0, 0, 0, 0, 0, 0, 0, 0};
  const float* w = Wg + (size_t)(threadIdx.x << 2) * 8;
#pragma unroll
  for (int j = 0; j < 4; ++j)
#pragma unroll
    for (int e = 0; e < 8; ++e) acc[e] += xt[j] * w[j * 8 + e];
#pragma unroll
  for (int e = 0; e < 8; ++e) acc[e] = wave_sum(acc[e]);
  __shared__ float red[4][8];
  const int lane = threadIdx.x & 63, wave = threadIdx.x >> 6;
  if (lane == 0) {
#pragma unroll
    for (int e = 0; e < 8; ++e) red[wave][e] = acc[e];
  }
  __syncthreads();
  if (threadIdx.x < 8)
    logits[(size_t)row * 8 + threadIdx.x] = red[0][threadIdx.x] +
        red[1][threadIdx.x] + red[2][threadIdx.x] + red[3][threadIdx.x];
}

__global__ void top2_k(const float* __restrict__ logits, int* __restrict__ topi,
                       float* __restrict__ gatew, int* __restrict__ counts) {
  const int t = blockIdx.x * 256 + threadIdx.x;
  if (t >= 4096) return;
  float l[8];
#pragma unroll
  for (int e = 0; e < 8; ++e) l[e] = logits[(size_t)t * 8 + e];
  int i0 = 0;
  float v0 = l[0];
#pragma unroll
  for (int e = 1; e < 8; ++e)
    if (l[e] > v0) { v0 = l[e]; i0 = e; }
  int i1 = -1;
  float v1 = -1e30f;
#pragma unroll
  for (int e = 0; e < 8; ++e)
    if (e != i0 && l[e] > v1) { v1 = l[e]; i1 = e; }
  const float g0 = 1.0f / (1.0f + __expf(v1 - v0));
  topi[2 * t] = i0;
  topi[2 * t + 1] = i1;
  gatew[2 * t] = g0;
  gatew[2 * t + 1] = 1.0f - g0;
  atomicAdd(&counts[i0], 1);
  atomicAdd(&counts[i1], 1);
}

__global__ void offsets_k(const int* __restrict__ counts, int* __restrict__ offs,
                          int* __restrict__ cursors) {
  if (threadIdx.x == 0) {
    int s = 0;
    for (int e = 0; e < 8; ++e) {
      offs[e] = s;
      s += counts[e];
    }
  }
  if (threadIdx.x < 8) cursors[threadIdx.x] = 0;
}

__global__ void route_k(const int* __restrict__ topi,
                        const float* __restrict__ gatew,
                        const int* __restrict__ offs, int* __restrict__ cursors,
                        int* __restrict__ token_ids,
                        float* __restrict__ tok_gate) {
  const int i = blockIdx.x * 256 + threadIdx.x;
  if (i >= 8192) return;
  const int t = i >> 1;
  const int e = topi[i];
  const float g = gatew[i];
  const int pos = offs[e] + atomicAdd(&cursors[e], 1);
  token_ids[pos] = t;
  tok_gate[pos] = g;
}

// out = x2 (residual) + gates @ b2; MoE GEMM2 atomically adds on top
__global__ void init_out_k(const float* __restrict__ X2,
                           const int* __restrict__ topi,
                           const float* __restrict__ gatew,
                           const float* __restrict__ b2,
                           float* __restrict__ Out) {
  const int row = blockIdx.x;
  float4 v = ((const float4*)(X2 + (size_t)row * 1024))[threadIdx.x];
  const int e0 = topi[2 * row], e1 = topi[2 * row + 1];
  const float g0 = gatew[2 * row], g1 = gatew[2 * row + 1];
  const float4 b0 = ((const float4*)(b2 + (size_t)e0 * 1024))[threadIdx.x];
  const float4 b1v = ((const float4*)(b2 + (size_t)e1 * 1024))[threadIdx.x];
  v.x += g0 * b0.x + g1 * b1v.x;
  v.y += g0 * b0.y + g1 * b1v.y;
  v.z += g0 * b0.z + g1 * b1v.z;
  v.w += g0 * b0.w + g1 * b1v.w;
  ((float4*)(Out + (size_t)row * 1024))[threadIdx.x] = v;
}

__global__ void cvt_k(const float* __restrict__ in, u16* __restrict__ out, int n4) {
  const int i = blockIdx.x * 256 + threadIdx.x;
  if (i >= n4) return;
  const float4 v = ((const float4*)in)[i];
  ushort4 o;
  o.x = f2b(v.x);
  o.y = f2b(v.y);
  o.z = f2b(v.z);
  o.w = f2b(v.w);
  ((ushort4*)out)[i] = o;
}

// [R,C] fp32 -> [C,R] bf16 per blockIdx.z slice
__global__ __launch_bounds__(256) void transpose_cvt_k(
    const float* __restrict__ in, u16* __restrict__ out, int R, int C) {
  __shared__ float tile[32][33];
  const size_t eo = (size_t)blockIdx.z * (size_t)R * C;
  in += eo;
  out += eo;
  const int cb = blockIdx.x << 5, rb = blockIdx.y << 5;
  const int tx = threadIdx.x & 31, ty = threadIdx.x >> 5;
#pragma unroll
  for (int i = 0; i < 4; ++i)
    tile[ty + i * 8][tx] = in[(size_t)(rb + ty + i * 8) * C + cb + tx];
  __syncthreads();
#pragma unroll
  for (int i = 0; i < 4; ++i)
    out[(size_t)(cb + ty + i * 8) * R + rb + tx] = f2b(tile[tx][ty + i * 8]);
}

__global__ void zero_k(int* __restrict__ counts) {
  if (threadIdx.x < 8) counts[threadIdx.x] = 0;
}

extern "C" void kernel_launch(void* const* d_in, const int* in_sizes, int n_in,
                              void* d_out, int out_size, void* d_ws,
                              size_t ws_size, hipStream_t stream) {
  (void)in_sizes; (void)n_in; (void)out_size;
  const float* x = (const float*)d_in[0];
  const float* ln1_g = (const float*)d_in[1];
  const float* ln1_b = (const float*)d_in[2];
  const float* qkv_w = (const float*)d_in[3];
  const float* qkv_b = (const float*)d_in[4];
  const float* out_w = (const float*)d_in[5];
  const float* out_b = (const float*)d_in[6];
  const float* ln2_g = (const float*)d_in[7];
  const float* ln2_b = (const float*)d_in[8];
  const float* Wg = (const float*)d_in[9];
  const float* W1 = (const float*)d_in[10];
  const float* b1 = (const float*)d_in[11];
  const float* W2 = (const float*)d_in[12];
  const float* b2 = (const float*)d_in[13];
  float* out = (float*)d_out;

  const int T = 4096, H = 1024, S = 2048, F = 4096, E = 8;

  char* p = (char*)d_ws;
  auto alloc = [&](size_t n) {
    char* r = p;
    p += (n + 255) & ~(size_t)255;
    return r;
  };
  u16* qkvw_bf = (u16*)alloc((size_t)3 * H * H * 2);
  u16* outw_bf = (u16*)alloc((size_t)H * H * 2);
  u16* W1t = (u16*)alloc((size_t)E * F * H * 2);
  u16* W2t = (u16*)alloc((size_t)E * H * F * 2);
  u16* h1bf = (u16*)alloc((size_t)T * H * 2);
  u16* qkvbf = (u16*)alloc((size_t)T * 3 * H * 2);
  u16* probs = (u16*)alloc((size_t)8 * S * S * 2);   // 4 heads x 2 batch chunk
  u16* obf = (u16*)alloc((size_t)T * H * 2);
  float* x2 = (float*)alloc((size_t)T * H * 4);
  u16* h2bf = (u16*)alloc((size_t)T * H * 2);
  u16* h1e = (u16*)alloc((size_t)2 * T * F * 2);
  float* logits = (float*)alloc((size_t)T * E * 4);
  float2* stats = (float2*)alloc((size_t)T * 8);
  int* topi = (int*)alloc((size_t)T * 2 * 4);
  float* gatew = (float*)alloc((size_t)T * 2 * 4);
  int* counts = (int*)alloc(64);
  int* offs = (int*)alloc(64);
  int* cursors = (int*)alloc(64);
  int* token_ids = (int*)alloc((size_t)2 * T * 4);
  float* tok_gate = (float*)alloc((size_t)2 * T * 4);
  if ((size_t)(p - (char*)d_ws) > ws_size) return;  // ws too small: bail

  zero_k<<<1, 64, 0, stream>>>(counts);
  cvt_k<<<(3 * H * H / 4 + 255) / 256, 256, 0, stream>>>(qkv_w, qkvw_bf, 3 * H * H / 4);
  cvt_k<<<(H * H / 4 + 255) / 256, 256, 0, stream>>>(out_w, outw_bf, H * H / 4);
  transpose_cvt_k<<<dim3(F / 32, H / 32, E), 256, 0, stream>>>(W1, W1t, H, F);
  transpose_cvt_k<<<dim3(H / 32, F / 32, E), 256, 0, stream>>>(W2, W2t, F, H);

  // LN1 -> bf16
  ln_k<<<T, 256, 0, stream>>>(x, ln1_g, ln1_b, h1bf, nullptr);

  // QKV: [T,1024] x [3072,1024]^T -> bf16 [T,3072]
  gemm_bt_k<EP_BF16, false><<<dim3(3 * H / 64, T / 64, 1), 256, 0, stream>>>(
      h1bf, H, qkvw_bf, H, qkv_b, nullptr, qkvbf, 3 * H, nullptr, T, 3 * H, H,
      1.0f, 1, 0, 0, 0, 0, 0, 0);

  // Attention: 4 groups of (2 batch x 4 heads)
  for (int g = 0; g < 4; ++g) {
    const u16* qb = qkvbf + g * 256;
    const u16* kb = qkvbf + 1024 + g * 256;
    const u16* vb = qkvbf + 2048 + g * 256;
    gemm_bt_k<EP_BF16, false><<<dim3(S / 64, S / 64, 8), 256, 0, stream>>>(
        qb, 3 * H, kb, 3 * H, nullptr, nullptr, probs, S, nullptr, S, S, 64,
        0.125f, 4, (long)S * 3 * H, 64, (long)S * 3 * H, 64, (long)4 * S * S,
        (long)S * S);
    softmax_k<<<8 * S, 256, 0, stream>>>(probs);
    gemm_bt_k<EP_BF16, true><<<dim3(1, S / 64, 8), 256, 0, stream>>>(
        probs, S, vb, 3 * H, nullptr, nullptr, obf + g * 256, H, nullptr, S, 64,
        S, 1.0f, 4, (long)4 * S * S, (long)S * S, (long)S * 3 * H, 64,
        (long)S * H, 64);
  }

  // out proj + residual -> x2 (fp32)
  gemm_bt_k<EP_F32RES, false><<<dim3(H / 64, T / 64, 1), 256, 0, stream>>>(
      obf, H, outw_bf, H, out_b, x2, nullptr, H, x, T, H, H, 1.0f, 1, 0, 0, 0,
      0, 0, 0);

  // LN2 (+stats), gating, routing
  ln_k<<<T, 256, 0, stream>>>(x2, ln2_g, ln2_b, h2bf, stats);
  logits_k<<<T, 256, 0, stream>>>(x2, stats, ln2_g, ln2_b, Wg, logits);
  top2_k<<<T / 256, 256, 0, stream>>>(logits, topi, gatew, counts);
  offsets_k<<<1, 64, 0, stream>>>(counts, offs, cursors);
  route_k<<<2 * T / 256, 256, 0, stream>>>(topi, gatew, offs, cursors, token_ids,
                                           tok_gate);
  init_out_k<<<T, 256, 0, stream>>>(x2, topi, gatew, b2, out);

  // Expert GEMMs (device-side M, early-exit blocks)
  moe_gemm1_k<<<dim3(F / 64, 2 * T / 64, E), 256, 0, stream>>>(
      h2bf, W1t, b1, counts, offs, token_ids, h1e);
  moe_gemm2_k<<<dim3(H / 64, 2 * T / 64, E), 256, 0, stream>>>(
      h1e, W2t, counts, offs, token_ids, tok_gate, out);
}

// Round 2
// 1209.523 us; speedup vs baseline: 1.1303x; 1.1303x over previous
//
#include <hip/hip_runtime.h>
#include <hip/hip_bf16.h>

typedef unsigned short u16;
typedef __bf16 bf16x8 __attribute__((ext_vector_type(8)));
typedef float f32x4 __attribute__((ext_vector_type(4)));
typedef __attribute__((address_space(3))) unsigned lds_u32;
typedef __attribute__((address_space(1))) const unsigned gbl_u32;

#define DI __device__ __forceinline__

DI u16 f2b(float f) {
  unsigned u = __builtin_bit_cast(unsigned, f);
  unsigned r = (u + 0x7FFFu + ((u >> 16) & 1u)) >> 16;
  return (u16)r;
}
DI float b2f(u16 h) {
  unsigned u = ((unsigned)h) << 16;
  return __builtin_bit_cast(float, u);
}
DI float wave_sum(float v) {
#pragma unroll
  for (int o = 32; o > 0; o >>= 1) v += __shfl_down(v, o);
  return v;
}
DI float wave_max(float v) {
#pragma unroll
  for (int o = 32; o > 0; o >>= 1) v = fmaxf(v, __shfl_down(v, o));
  return v;
}
DI float gelu_tanh(float v) {
  float u = 0.7978845608028654f * (v + 0.044715f * v * v * v);
  float eu = __expf(-2.0f * fabsf(u));
  float th = (1.0f - eu) / (1.0f + eu);
  th = (u < 0.0f) ? -th : th;
  return 0.5f * v * (1.0f + th);
}

// Async global->LDS, 16B per lane. LDS dest is wave-uniform base + lane*16
// (m104/m108): tile rows must be stored contiguous (row stride 64B, no pad).
DI void gld_lds16(const u16* g, u16* l) {
  __builtin_amdgcn_global_load_lds((gbl_u32*)g, (lds_u32*)l, 16, 0, 0);
}

// ---------------------------------------------------------------------------
// m97-class GEMM core. Block = 256 thr = 4 waves in 2x2 grid; wave computes
// (MT*16) x (NT*16); block tile BM=MT*32 x BN=NT*32. BK=32. A[M,K], B=Bt[N,K]
// both row-major bf16. LDS tiles are row-contiguous (stride 32 elem = 64B) as
// required by global_load_lds. K must be a multiple of 32; all staged rows
// must be readable (callers over-allocate edge garbage and mask stores).
// ---------------------------------------------------------------------------
template <int MT, int NT>
DI void gemm_core(const u16* __restrict__ A, long lda, const u16* __restrict__ B,
                  long ldb, int K, u16* As, u16* Bs, f32x4 acc[MT][NT]) {
  const int t = threadIdx.x, lane = t & 63, wave = t >> 6;
  const int wm = (wave >> 1) * (MT * 16), wn = (wave & 1) * (NT * 16);
  const int sr = lane >> 2;          // staged row within 16-row issue
  const int sc = (lane & 3) << 3;    // staged k chunk (elements)
  const int fr = lane & 15;          // fragment row
  const int fk = (lane >> 4) << 3;   // fragment k offset
  for (int kb = 0; kb < K; kb += 32) {
#pragma unroll
    for (int ii = 0; ii < MT / 2; ++ii) {
      const int i = ii * 4 + wave;   // 16-row issue index
      gld_lds16(A + (size_t)(i * 16 + sr) * lda + kb + sc, As + i * 512);
    }
#pragma unroll
    for (int ii = 0; ii < NT / 2; ++ii) {
      const int i = ii * 4 + wave;
      gld_lds16(B + (size_t)(i * 16 + sr) * ldb + kb + sc, Bs + i * 512);
    }
    __syncthreads();
    bf16x8 af[MT], bfr[NT];
#pragma unroll
    for (int m = 0; m < MT; ++m)
      af[m] = *(const bf16x8*)(As + (wm + m * 16 + fr) * 32 + fk);
#pragma unroll
    for (int n = 0; n < NT; ++n)
      bfr[n] = *(const bf16x8*)(Bs + (wn + n * 16 + fr) * 32 + fk);
#pragma unroll
    for (int m = 0; m < MT; ++m)
#pragma unroll
      for (int n = 0; n < NT; ++n)
        acc[m][n] =
            __builtin_amdgcn_mfma_f32_16x16x32_bf16(af[m], bfr[n], acc[m][n], 0, 0, 0);
    __syncthreads();
  }
}

constexpr int EP_BF16 = 0;
constexpr int EP_F32RES = 1;

// Generic batched GEMM; z = (zb,zh) with independent strides (elements).
// All M/N dims are exact tile multiples for every use of this kernel.
template <int EP, int MT, int NT>
__global__ __launch_bounds__(256) void gemm_k(
    const u16* __restrict__ A, long lda, const u16* __restrict__ B, long ldb,
    const float* __restrict__ bias, float alpha, float* __restrict__ Cf,
    u16* __restrict__ Cb, long ldc, const float* __restrict__ resid, int K,
    int Zh, long sAb, long sAh, long sBb, long sBh, long sCb, long sCh) {
  constexpr int BM = MT * 32, BN = NT * 32;
  __shared__ __align__(16) u16 As[BM * 32];
  __shared__ __align__(16) u16 Bs[BN * 32];
  const int z = blockIdx.z, zb = z / Zh, zh = z - zb * Zh;
  const long m_base = (long)blockIdx.y * BM, n_base = (long)blockIdx.x * BN;
  const u16* Ap = A + zb * sAb + zh * sAh + m_base * lda;
  const u16* Bp = B + zb * sBb + zh * sBh + n_base * ldb;
  const long coff = zb * sCb + zh * sCh;
  f32x4 acc[MT][NT];
  const f32x4 z4 = {0.f, 0.f, 0.f, 0.f};
#pragma unroll
  for (int m = 0; m < MT; ++m)
#pragma unroll
    for (int n = 0; n < NT; ++n) acc[m][n] = z4;
  gemm_core<MT, NT>(Ap, lda, Bp, ldb, K, As, Bs, acc);
  const int lane = threadIdx.x & 63, wave = threadIdx.x >> 6;
  const int wm = (wave >> 1) * (MT * 16), wn = (wave & 1) * (NT * 16);
  const int r0 = wm + ((lane >> 4) << 2), c0 = lane & 15;
#pragma unroll
  for (int n = 0; n < NT; ++n) {
    const long gn = n_base + wn + n * 16 + c0;
    const float bv = bias ? bias[gn] : 0.0f;
#pragma unroll
    for (int m = 0; m < MT; ++m)
#pragma unroll
      for (int r = 0; r < 4; ++r) {
        const long gm = m_base + r0 + m * 16 + r;
        const float v = acc[m][n][r] * alpha + bv;
        if (EP == EP_F32RES)
          Cf[coff + gm * ldc + gn] = v + resid[gm * ldc + gn];
        else
          Cb[coff + gm * ldc + gn] = f2b(v);
      }
  }
}

// Expert GEMM1: Xg (contiguous routed tokens) x W1t[e]^T, gelu -> H1 (bf16).
__global__ __launch_bounds__(256) void moe_gemm1_k(
    const u16* __restrict__ Xg, const u16* __restrict__ W1t,
    const float* __restrict__ b1, const int* __restrict__ counts,
    const int* __restrict__ offs, u16* __restrict__ H1) {
  __shared__ __align__(16) u16 As[128 * 32];
  __shared__ __align__(16) u16 Bs[128 * 32];
  const int e = blockIdx.z;
  const int Me = counts[e];
  const int m_base = blockIdx.y << 7;
  if (m_base >= Me) return;
  const int off_e = offs[e];
  const long n_base = (long)blockIdx.x << 7;
  const u16* A = Xg + (size_t)(off_e + m_base) * 1024;
  const u16* B = W1t + (size_t)e * 4096 * 1024 + n_base * 1024;
  f32x4 acc[4][4];
  const f32x4 z4 = {0.f, 0.f, 0.f, 0.f};
#pragma unroll
  for (int m = 0; m < 4; ++m)
#pragma unroll
    for (int n = 0; n < 4; ++n) acc[m][n] = z4;
  gemm_core<4, 4>(A, 1024, B, 1024, 1024, As, Bs, acc);
  const int M_rem = Me - m_base;
  const int lane = threadIdx.x & 63, wave = threadIdx.x >> 6;
  const int wm = (wave >> 1) << 6, wn = (wave & 1) << 6;
  const int r0 = wm + ((lane >> 4) << 2), c0 = lane & 15;
  const float* b1e = b1 + (size_t)e * 4096;
#pragma unroll
  for (int n = 0; n < 4; ++n) {
    const long gn = n_base + wn + n * 16 + c0;
    const float bv = b1e[gn];
#pragma unroll
    for (int m = 0; m < 4; ++m)
#pragma unroll
      for (int r = 0; r < 4; ++r) {
        const int ml = r0 + m * 16 + r;
        if (ml >= M_rem) continue;
        H1[(size_t)(off_e + m_base + ml) * 4096 + gn] = f2b(gelu_tanh(acc[m][n][r] + bv));
      }
  }
}

// Expert GEMM2: H1 x W2t[e]^T -> per-slot Ye (fp32, ungated).
__global__ __launch_bounds__(256) void moe_gemm2_k(
    const u16* __restrict__ H1, const u16* __restrict__ W2t,
    const int* __restrict__ counts, const int* __restrict__ offs,
    float* __restrict__ Ye) {
  __shared__ __align__(16) u16 As[128 * 32];
  __shared__ __align__(16) u16 Bs[128 * 32];
  const int e = blockIdx.z;
  const int Me = counts[e];
  const int m_base = blockIdx.y << 7;
  if (m_base >= Me) return;
  const int off_e = offs[e];
  const long n_base = (long)blockIdx.x << 7;
  const u16* A = H1 + (size_t)(off_e + m_base) * 4096;
  const u16* B = W2t + (size_t)e * 1024 * 4096 + n_base * 4096;
  f32x4 acc[4][4];
  const f32x4 z4 = {0.f, 0.f, 0.f, 0.f};
#pragma unroll
  for (int m = 0; m < 4; ++m)
#pragma unroll
    for (int n = 0; n < 4; ++n) acc[m][n] = z4;
  gemm_core<4, 4>(A, 4096, B, 4096, 4096, As, Bs, acc);
  const int M_rem = Me - m_base;
  const int lane = threadIdx.x & 63, wave = threadIdx.x >> 6;
  const int wm = (wave >> 1) << 6, wn = (wave & 1) << 6;
  const int r0 = wm + ((lane >> 4) << 2), c0 = lane & 15;
#pragma unroll
  for (int m = 0; m < 4; ++m)
#pragma unroll
    for (int r = 0; r < 4; ++r) {
      const int ml = r0 + m * 16 + r;
      if (ml >= M_rem) continue;
      float* yrow = Ye + (size_t)(off_e + m_base + ml) * 1024 + n_base;
#pragma unroll
      for (int n = 0; n < 4; ++n) yrow[wn + n * 16 + c0] = acc[m][n][r];
    }
}

// LayerNorm over 1024 cols, writes bf16 (+ optional per-row stats)
__global__ __launch_bounds__(256) void ln_k(const float* __restrict__ X,
                                            const float* __restrict__ g,
                                            const float* __restrict__ b,
                                            u16* __restrict__ Y,
                                            float2* __restrict__ stats) {
  const int row = blockIdx.x;
  const float4 xv = ((const float4*)(X + (size_t)row * 1024))[threadIdx.x];
  float s = xv.x + xv.y + xv.z + xv.w;
  float s2 = xv.x * xv.x + xv.y * xv.y + xv.z * xv.z + xv.w * xv.w;
  s = wave_sum(s);
  s2 = wave_sum(s2);
  __shared__ float rs_[4], r2_[4];
  const int lane = threadIdx.x & 63, wave = threadIdx.x >> 6;
  if (lane == 0) { rs_[wave] = s; r2_[wave] = s2; }
  __syncthreads();
  const float tot = rs_[0] + rs_[1] + rs_[2] + rs_[3];
  const float tot2 = r2_[0] + r2_[1] + r2_[2] + r2_[3];
  const float mu = tot * (1.0f / 1024.0f);
  const float var = tot2 * (1.0f / 1024.0f) - mu * mu;
  const float rstd = rsqrtf(var + 1e-5f);
  const float4 gv = ((const float4*)g)[threadIdx.x];
  const float4 bv = ((const float4*)b)[threadIdx.x];
  ushort4 o;
  o.x = f2b((xv.x - mu) * rstd * gv.x + bv.x);
  o.y = f2b((xv.y - mu) * rstd * gv.y + bv.y);
  o.z = f2b((xv.z - mu) * rstd * gv.z + bv.z);
  o.w = f2b((xv.w - mu) * rstd * gv.w + bv.w);
  ((ushort4*)(Y + (size_t)row * 1024))[threadIdx.x] = o;
  if (stats != nullptr && threadIdx.x == 0) stats[row] = make_float2(mu, rstd);
}

// Softmax over 2048-wide bf16 rows, in place
__global__ __launch_bounds__(256) void softmax_k(u16* __restrict__ P) {
  uint4* row = (uint4*)(P + (size_t)blockIdx.x * 2048);
  uint4 raw = row[threadIdx.x];
  u16* us = (u16*)&raw;
  float f[8];
  float mx = -1e30f;
#pragma unroll
  for (int j = 0; j < 8; ++j) {
    f[j] = b2f(us[j]);
    mx = fmaxf(mx, f[j]);
  }
  mx = wave_max(mx);
  __shared__ float redm[4], redsum[4];
  const int lane = threadIdx.x & 63, wave = threadIdx.x >> 6;
  if (lane == 0) redm[wave] = mx;
  __syncthreads();
  mx = fmaxf(fmaxf(redm[0], redm[1]), fmaxf(redm[2], redm[3]));
  float sum = 0.0f;
#pragma unroll
  for (int j = 0; j < 8; ++j) {
    f[j] = __expf(f[j] - mx);
    sum += f[j];
  }
  sum = wave_sum(sum);
  if (lane == 0) redsum[wave] = sum;
  __syncthreads();
  sum = redsum[0] + redsum[1] + redsum[2] + redsum[3];
  const float inv = 1.0f / sum;
#pragma unroll
  for (int j = 0; j < 8; ++j) us[j] = f2b(f[j] * inv);
  row[threadIdx.x] = raw;
}

// Gating logits in fp32 (LN recomputed exactly from stats: avoids bf16 top-2 flips)
__global__ __launch_bounds__(256) void logits_k(
    const float* __restrict__ X2, const float2* __restrict__ stats,
    const float* __restrict__ g, const float* __restrict__ b,
    const float* __restrict__ Wg, float* __restrict__ logits) {
  const int row = blockIdx.x;
  const float2 st = stats[row];
  const float4 xv = ((const float4*)(X2 + (size_t)row * 1024))[threadIdx.x];
  const float4 gv = ((const float4*)g)[threadIdx.x];
  const float4 bv = ((const float4*)b)[threadIdx.x];
  float xt[4];
  xt[0] = (xv.x - st.x) * st.y * gv.x + bv.x;
  xt[1] = (xv.y - st.x) * st.y * gv.y + bv.y;
  xt[2] = (xv.z - st.x) * st.y * gv.z + bv.z;
  xt[3] = (xv.w - st.x) * st.y * gv.w + bv.w;
  float acc[8] = {0, 0, 0, 0, 0, 0, 0, 0};
  const float* w = Wg + (size_t)(threadIdx.x << 2) * 8;
#pragma unroll
  for (int j = 0; j < 4; ++j)
#pragma unroll
    for (int e = 0; e < 8; ++e) acc[e] += xt[j] * w[j * 8 + e];
#pragma unroll
  for (int e = 0; e < 8; ++e) acc[e] = wave_sum(acc[e]);
  __shared__ float red[4][8];
  const int lane = threadIdx.x & 63, wave = threadIdx.x >> 6;
  if (lane == 0) {
#pragma unroll
    for (int e = 0; e < 8; ++e) red[wave][e] = acc[e];
  }
  __syncthreads();
  if (threadIdx.x < 8)
    logits[(size_t)row * 8 + threadIdx.x] = red[0][threadIdx.x] +
        red[1][threadIdx.x] + red[2][threadIdx.x] + red[3][threadIdx.x];
}

__global__ void top2_k(const float* __restrict__ logits, int* __restrict__ topi,
                       float* __restrict__ gatew, int* __restrict__ counts) {
  const int t = blockIdx.x * 256 + threadIdx.x;
  if (t >= 4096) return;
  float l[8];
#pragma unroll
  for (int e = 0; e < 8; ++e) l[e] = logits[(size_t)t * 8 + e];
  int i0 = 0;
  float v0 = l[0];
#pragma unroll
  for (int e = 1; e < 8; ++e)
    if (l[e] > v0) { v0 = l[e]; i0 = e; }
  int i1 = -1;
  float v1 = -1e30f;
#pragma unroll
  for (int e = 0; e < 8; ++e)
    if (e != i0 && l[e] > v1) { v1 = l[e]; i1 = e; }
  const float g0 = 1.0f / (1.0f + __expf(v1 - v0));
  topi[2 * t] = i0;
  topi[2 * t + 1] = i1;
  gatew[2 * t] = g0;
  gatew[2 * t + 1] = 1.0f - g0;
  atomicAdd(&counts[i0], 1);
  atomicAdd(&counts[i1], 1);
}

__global__ void offsets_k(const int* __restrict__ counts, int* __restrict__ offs,
                          int* __restrict__ cursors) {
  if (threadIdx.x == 0) {
    int s = 0;
    for (int e = 0; e < 8; ++e) {
      offs[e] = s;
      s += counts[e];
    }
  }
  if (threadIdx.x < 8) cursors[threadIdx.x] = 0;
}

__global__ void route_k(const int* __restrict__ topi,
                        const int* __restrict__ offs, int* __restrict__ cursors,
                        int* __restrict__ token_ids, int* __restrict__ tok2slot) {
  const int i = blockIdx.x * 256 + threadIdx.x;
  if (i >= 8192) return;
  const int t = i >> 1;
  const int e = topi[i];
  const int pos = offs[e] + atomicAdd(&cursors[e], 1);
  token_ids[pos] = t;
  tok2slot[i] = pos;
}

// Gather routed tokens into contiguous Xg (8192 slots x 1024 bf16)
__global__ void gather_k(const u16* __restrict__ X,
                         const int* __restrict__ token_ids,
                         u16* __restrict__ Xg) {
  const int i = blockIdx.x * 256 + threadIdx.x;  // one uint4 (8 bf16) each
  const int slot = i >> 7, c = i & 127;
  ((uint4*)Xg)[(size_t)slot * 128 + c] =
      ((const uint4*)X)[(size_t)token_ids[slot] * 128 + c];
}

// out = x2 + g0*(Ye[s0]+b2[e0]) + g1*(Ye[s1]+b2[e1])
__global__ void combine_k(const float* __restrict__ X2,
                          const int* __restrict__ topi,
                          const float* __restrict__ gatew,
                          const int* __restrict__ tok2slot,
                          const float* __restrict__ Ye,
                          const float* __restrict__ b2,
                          float* __restrict__ Out) {
  const int t = blockIdx.x;
  float4 v = ((const float4*)(X2 + (size_t)t * 1024))[threadIdx.x];
  const int e0 = topi[2 * t], e1 = topi[2 * t + 1];
  const float g0 = gatew[2 * t], g1 = gatew[2 * t + 1];
  const int s0 = tok2slot[2 * t], s1 = tok2slot[2 * t + 1];
  const float4 y0 = ((const float4*)(Ye + (size_t)s0 * 1024))[threadIdx.x];
  const float4 y1 = ((const float4*)(Ye + (size_t)s1 * 1024))[threadIdx.x];
  const float4 c0 = ((const float4*)(b2 + (size_t)e0 * 1024))[threadIdx.x];
  const float4 c1 = ((const float4*)(b2 + (size_t)e1 * 1024))[threadIdx.x];
  v.x += g0 * (y0.x + c0.x) + g1 * (y1.x + c1.x);
  v.y += g0 * (y0.y + c0.y) + g1 * (y1.y + c1.y);
  v.z += g0 * (y0.z + c0.z) + g1 * (y1.z + c1.z);
  v.w += g0 * (y0.w + c0.w) + g1 * (y1.w + c1.w);
  ((float4*)(Out + (size_t)t * 1024))[threadIdx.x] = v;
}

__global__ void cvt_k(const float* __restrict__ in, u16* __restrict__ out, int n4) {
  const int i = blockIdx.x * 256 + threadIdx.x;
  if (i >= n4) return;
  const float4 v = ((const float4*)in)[i];
  ushort4 o;
  o.x = f2b(v.x);
  o.y = f2b(v.y);
  o.z = f2b(v.z);
  o.w = f2b(v.w);
  ((ushort4*)out)[i] = o;
}

// [R,C] fp32 -> [C,R] bf16 per blockIdx.z slice
__global__ __launch_bounds__(256) void transpose_cvt_k(
    const float* __restrict__ in, u16* __restrict__ out, int R, int C) {
  __shared__ float tile[32][33];
  const size_t eo = (size_t)blockIdx.z * (size_t)R * C;
  in += eo;
  out += eo;
  const int cb = blockIdx.x << 5, rb = blockIdx.y << 5;
  const int tx = threadIdx.x & 31, ty = threadIdx.x >> 5;
#pragma unroll
  for (int i = 0; i < 4; ++i)
    tile[ty + i * 8][tx] = in[(size_t)(rb + ty + i * 8) * C + cb + tx];
  __syncthreads();
#pragma unroll
  for (int i = 0; i < 4; ++i)
    out[(size_t)(cb + ty + i * 8) * R + rb + tx] = f2b(tile[tx][ty + i * 8]);
}

// V columns of qkv [T,3072] -> Vt[bh][64,2048] bf16
__global__ __launch_bounds__(256) void vtrans_k(const u16* __restrict__ qkv,
                                                u16* __restrict__ Vt) {
  __shared__ u16 tile[32][33];
  const int z = blockIdx.z, b = z >> 4, h = z & 15;
  const int sb = blockIdx.x << 5;  // seq tile
  const int db = blockIdx.y << 5;  // head-dim tile (0 or 32)
  const int tx = threadIdx.x & 31, ty = threadIdx.x >> 5;
  const u16* src = qkv + ((size_t)b * 2048) * 3072 + 2048 + h * 64;
#pragma unroll
  for (int i = 0; i < 4; ++i)
    tile[ty + i * 8][tx] = src[(size_t)(sb + ty + i * 8) * 3072 + db + tx];
  __syncthreads();
  u16* dst = Vt + ((size_t)z * 64 + db) * 2048 + sb;
#pragma unroll
  for (int i = 0; i < 4; ++i)
    dst[(size_t)(ty + i * 8) * 2048 + tx] = tile[tx][ty + i * 8];
}

__global__ void zero_k(int* __restrict__ counts) {
  if (threadIdx.x < 8) counts[threadIdx.x] = 0;
}

extern "C" void kernel_launch(void* const* d_in, const int* in_sizes, int n_in,
                              void* d_out, int out_size, void* d_ws,
                              size_t ws_size, hipStream_t stream) {
  (void)in_sizes; (void)n_in; (void)out_size;
  const float* x = (const float*)d_in[0];
  const float* ln1_g = (const float*)d_in[1];
  const float* ln1_b = (const float*)d_in[2];
  const float* qkv_w = (const float*)d_in[3];
  const float* qkv_b = (const float*)d_in[4];
  const float* out_w = (const float*)d_in[5];
  const float* out_b = (const float*)d_in[6];
  const float* ln2_g = (const float*)d_in[7];
  const float* ln2_b = (const float*)d_in[8];
  const float* Wg = (const float*)d_in[9];
  const float* W1 = (const float*)d_in[10];
  const float* b1 = (const float*)d_in[11];
  const float* W2 = (const float*)d_in[12];
  const float* b2 = (const float*)d_in[13];
  float* out = (float*)d_out;

  const int T = 4096, H = 1024, S = 2048, F = 4096, E = 8;
  const long SS = (long)S * S;

  char* p = (char*)d_ws;
  auto alloc = [&](size_t n) {
    char* r = p;
    p += (n + 255) & ~(size_t)255;
    return r;
  };
  u16* qkvw_bf = (u16*)alloc((size_t)3 * H * H * 2);
  u16* outw_bf = (u16*)alloc((size_t)H * H * 2);
  u16* W1t = (u16*)alloc((size_t)E * F * H * 2);
  u16* W2t = (u16*)alloc((size_t)E * H * F * 2);
  u16* h1bf = (u16*)alloc((size_t)T * H * 2);    // also reused as Vt (same size)
  u16* qkvbf = (u16*)alloc((size_t)T * 3 * H * 2);
  u16* probs = (u16*)alloc((size_t)8 * SS * 2);  // later: Ye + Xg overlay
  u16* obf = (u16*)alloc((size_t)T * H * 2);     // also reused as h2bf
  float* x2 = (float*)alloc((size_t)T * H * 4);
  u16* H1 = (u16*)alloc((size_t)(2 * T + 128) * F * 2);
  float* logits = (float*)alloc((size_t)T * E * 4);
  float2* stats = (float2*)alloc((size_t)T * 8);
  int* topi = (int*)alloc((size_t)T * 2 * 4);
  float* gatew = (float*)alloc((size_t)T * 2 * 4);
  int* counts = (int*)alloc(64);
  int* offs = (int*)alloc(64);
  int* cursors = (int*)alloc(64);
  int* token_ids = (int*)alloc((size_t)(2 * T + 128) * 4);
  int* tok2slot = (int*)alloc((size_t)2 * T * 4);
  if ((size_t)(p - (char*)d_ws) > ws_size) return;  // ws too small: bail

  // Overlays (lifetimes disjoint from original owner):
  u16* Vt = h1bf;                                   // after QKV gemm
  u16* h2bf = obf;                                  // after out-proj
  float* Ye = (float*)probs;                        // after attention (33.5MB)
  u16* Xg = (u16*)((char*)probs + (size_t)T * H * 8);  // +33.5MB, 17MB

  zero_k<<<1, 64, 0, stream>>>(counts);
  cvt_k<<<3 * H * H / 4 / 256, 256, 0, stream>>>(qkv_w, qkvw_bf, 3 * H * H / 4);
  cvt_k<<<H * H / 4 / 256, 256, 0, stream>>>(out_w, outw_bf, H * H / 4);
  transpose_cvt_k<<<dim3(F / 32, H / 32, E), 256, 0, stream>>>(W1, W1t, H, F);
  transpose_cvt_k<<<dim3(H / 32, F / 32, E), 256, 0, stream>>>(W2, W2t, F, H);

  // LN1 -> bf16
  ln_k<<<T, 256, 0, stream>>>(x, ln1_g, ln1_b, h1bf, nullptr);

  // QKV: [T,1024] x [3072,1024]^T -> bf16 [T,3072]
  gemm_k<EP_BF16, 4, 4><<<dim3(3 * H / 128, T / 128, 1), 256, 0, stream>>>(
      h1bf, H, qkvw_bf, H, qkv_b, 1.0f, nullptr, qkvbf, 3 * H, nullptr, H, 1,
      0, 0, 0, 0, 0, 0);

  // V -> Vt[bh][64,2048] (h1bf reuse begins here; QKV gemm is done with it)
  vtrans_k<<<dim3(S / 32, 2, 32), 256, 0, stream>>>(qkvbf, Vt);

  // Attention: 4 groups of (2 batch x 4 heads)
  for (int g = 0; g < 4; ++g) {
    const u16* qb = qkvbf + g * 256;
    const u16* kb = qkvbf + 1024 + g * 256;
    // scores = Q K^T / 8 -> probs (bf16)
    gemm_k<EP_BF16, 4, 4><<<dim3(S / 128, S / 128, 8), 256, 0, stream>>>(
        qb, 3 * H, kb, 3 * H, nullptr, 0.125f, nullptr, probs, S, nullptr, 64,
        4, (long)S * 3 * H, 64, (long)S * 3 * H, 64, 4 * SS, SS);
    softmax_k<<<8 * S, 256, 0, stream>>>(probs);
    // O = P V -> obf cols [g*256 + zh*64, +64)
    gemm_k<EP_BF16, 4, 2><<<dim3(1, S / 128, 8), 256, 0, stream>>>(
        probs, S, Vt + (size_t)g * 4 * 64 * S, S, nullptr, 1.0f, nullptr,
        obf + g * 256, H, nullptr, S, 4, 4 * SS, SS, (long)16 * 64 * S,
        (long)64 * S, (long)S * H, 64);
  }

  // out proj + residual -> x2 (fp32)
  gemm_k<EP_F32RES, 4, 4><<<dim3(H / 128, T / 128, 1), 256, 0, stream>>>(
      obf, H, outw_bf, H, out_b, 1.0f, x2, nullptr, H, x, H, 1, 0, 0, 0, 0, 0,
      0);

  // LN2 (+stats), gating, routing (obf is dead; h2bf reuses it)
  ln_k<<<T, 256, 0, stream>>>(x2, ln2_g, ln2_b, h2bf, stats);
  logits_k<<<T, 256, 0, stream>>>(x2, stats, ln2_g, ln2_b, Wg, logits);
  top2_k<<<T / 256, 256, 0, stream>>>(logits, topi, gatew, counts);
  offsets_k<<<1, 64, 0, stream>>>(counts, offs, cursors);
  route_k<<<2 * T / 256, 256, 0, stream>>>(topi, offs, cursors, token_ids,
                                           tok2slot);
  // Contiguous routed-token copy (probs is dead; Xg/Ye overlay it)
  gather_k<<<2 * T * (H / 8) / 256, 256, 0, stream>>>(h2bf, token_ids, Xg);

  // Expert GEMMs (device-side M, early-exit blocks)
  moe_gemm1_k<<<dim3(F / 128, T / 128, E), 256, 0, stream>>>(Xg, W1t, b1,
                                                             counts, offs, H1);
  moe_gemm2_k<<<dim3(H / 128, T / 128, E), 256, 0, stream>>>(H1, W2t, counts,
                                                             offs, Ye);

  // Final combine: residual + gated expert outputs + gate-weighted b2
  combine_k<<<T, 256, 0, stream>>>(x2, topi, gatew, tok2slot, Ye, b2, out);
}

// Round 3
// 992.421 us; speedup vs baseline: 1.3775x; 1.2188x over previous
//
#include <hip/hip_runtime.h>
#include <hip/hip_bf16.h>

typedef unsigned short u16;
typedef __bf16 bf16x8 __attribute__((ext_vector_type(8)));
typedef float f32x4 __attribute__((ext_vector_type(4)));
typedef __attribute__((address_space(3))) unsigned lds_u32;
typedef __attribute__((address_space(1))) const unsigned gbl_u32;

#define DI __device__ __forceinline__

DI u16 f2b(float f) {
  unsigned u = __builtin_bit_cast(unsigned, f);
  unsigned r = (u + 0x7FFFu + ((u >> 16) & 1u)) >> 16;
  return (u16)r;
}
DI float b2f(u16 h) {
  unsigned u = ((unsigned)h) << 16;
  return __builtin_bit_cast(float, u);
}
DI float wave_sum(float v) {
#pragma unroll
  for (int o = 32; o > 0; o >>= 1) v += __shfl_down(v, o);
  return v;
}
DI float gelu_tanh(float v) {
  float u = 0.7978845608028654f * (v + 0.044715f * v * v * v);
  float eu = __expf(-2.0f * fabsf(u));
  float th = (1.0f - eu) / (1.0f + eu);
  th = (u < 0.0f) ? -th : th;
  return 0.5f * v * (1.0f + th);
}

// Async global->LDS, 16B per lane. LDS dest is wave-uniform base + lane*16.
DI void gld_lds16(const u16* g, u16* l) {
  __builtin_amdgcn_global_load_lds((gbl_u32*)g, (lds_u32*)l, 16, 0, 0);
}

// ---------------------------------------------------------------------------
// m97-class GEMM core, BK=32, LDS row stride 32 elem (64B) contiguous.
// XOR swizzle: lane stages global chunk (lane&3)^((row_in_16>>1)&3) so the
// fixed lane->LDS mapping of global_load_lds lands a bank-spread layout;
// fragment reads apply the same XOR. 8-way conflicts -> 2-way (free, m136).
// ---------------------------------------------------------------------------
template <int MT, int NT>
DI void gemm_core(const u16* __restrict__ A, long lda, const u16* __restrict__ B,
                  long ldb, int K, u16* As, u16* Bs, f32x4 acc[MT][NT]) {
  const int t = threadIdx.x, lane = t & 63, wave = t >> 6;
  const int wm = (wave >> 1) * (MT * 16), wn = (wave & 1) * (NT * 16);
  const int sr = lane >> 2;                                  // row within 16
  const int sc = (((lane & 3) ^ ((lane >> 3) & 3)) << 3);    // swizzled chunk
  const int fr = lane & 15;
  const int fk = ((((lane >> 4) ^ ((fr >> 1) & 3))) << 3);   // swizzled frag k
  for (int kb = 0; kb < K; kb += 32) {
#pragma unroll
    for (int ii = 0; ii < MT / 2; ++ii) {
      const int i = ii * 4 + wave;
      gld_lds16(A + (size_t)(i * 16 + sr) * lda + kb + sc, As + i * 512);
    }
#pragma unroll
    for (int ii = 0; ii < NT / 2; ++ii) {
      const int i = ii * 4 + wave;
      gld_lds16(B + (size_t)(i * 16 + sr) * ldb + kb + sc, Bs + i * 512);
    }
    __syncthreads();
    bf16x8 af[MT], bfr[NT];
#pragma unroll
    for (int m = 0; m < MT; ++m)
      af[m] = *(const bf16x8*)(As + (wm + m * 16 + fr) * 32 + fk);
#pragma unroll
    for (int n = 0; n < NT; ++n)
      bfr[n] = *(const bf16x8*)(Bs + (wn + n * 16 + fr) * 32 + fk);
#pragma unroll
    for (int m = 0; m < MT; ++m)
#pragma unroll
      for (int n = 0; n < NT; ++n)
        acc[m][n] =
            __builtin_amdgcn_mfma_f32_16x16x32_bf16(af[m], bfr[n], acc[m][n], 0, 0, 0);
    __syncthreads();
  }
}

constexpr int EP_BF16 = 0;
constexpr int EP_F32RES = 1;

template <int EP, int MT, int NT>
__global__ __launch_bounds__(256) void gemm_k(
    const u16* __restrict__ A, long lda, const u16* __restrict__ B, long ldb,
    const float* __restrict__ bias, float alpha, float* __restrict__ Cf,
    u16* __restrict__ Cb, long ldc, const float* __restrict__ resid, int K) {
  constexpr int BM = MT * 32, BN = NT * 32;
  __shared__ __align__(16) u16 As[BM * 32];
  __shared__ __align__(16) u16 Bs[BN * 32];
  const long m_base = (long)blockIdx.y * BM, n_base = (long)blockIdx.x * BN;
  const u16* Ap = A + m_base * lda;
  const u16* Bp = B + n_base * ldb;
  f32x4 acc[MT][NT];
  const f32x4 z4 = {0.f, 0.f, 0.f, 0.f};
#pragma unroll
  for (int m = 0; m < MT; ++m)
#pragma unroll
    for (int n = 0; n < NT; ++n) acc[m][n] = z4;
  gemm_core<MT, NT>(Ap, lda, Bp, ldb, K, As, Bs, acc);
  const int lane = threadIdx.x & 63, wave = threadIdx.x >> 6;
  const int wm = (wave >> 1) * (MT * 16), wn = (wave & 1) * (NT * 16);
  const int r0 = wm + ((lane >> 4) << 2), c0 = lane & 15;
#pragma unroll
  for (int n = 0; n < NT; ++n) {
    const long gn = n_base + wn + n * 16 + c0;
    const float bv = bias ? bias[gn] : 0.0f;
#pragma unroll
    for (int m = 0; m < MT; ++m)
#pragma unroll
      for (int r = 0; r < 4; ++r) {
        const long gm = m_base + r0 + m * 16 + r;
        const float v = acc[m][n][r] * alpha + bv;
        if (EP == EP_F32RES)
          Cf[gm * ldc + gn] = v + resid[gm * ldc + gn];
        else
          Cb[gm * ldc + gn] = f2b(v);
      }
  }
}

// ---------------------------------------------------------------------------
// Flash attention: grid (S/128, B*NH). Q-tile 128, KV-tile 64, D=64.
// S computed transposed (S^T = K.Q^T) so C/D reg dim (4 consecutive rows=kv)
// is contiguous in P[q][kv] (stride 72 elem, pad kills write conflicts).
// Online-softmax m/l state lives in regs of thread t owning row q=t>>1.
// ---------------------------------------------------------------------------
__global__ __launch_bounds__(256) void flash_attn_k(const u16* __restrict__ qkv,
                                                    const u16* __restrict__ Vt,
                                                    u16* __restrict__ O) {
  __shared__ __align__(16) u16 Qs[128 * 64];
  __shared__ __align__(16) u16 Ks[64 * 64];
  __shared__ __align__(16) u16 Vs[64 * 64];
  __shared__ __align__(16) u16 Ps[128 * 72];
  __shared__ __align__(16) float alpha_s[128];
  __shared__ __align__(16) float linv_s[128];
  const int t = threadIdx.x, lane = t & 63, wave = t >> 6;
  const int bh = blockIdx.y, b = bh >> 4, h = bh & 15;
  const int q0 = blockIdx.x << 7;
  const u16* Qg = qkv + ((size_t)(b * 2048 + q0)) * 3072 + h * 64;
  const u16* Kg = qkv + ((size_t)b * 2048) * 3072 + 1024 + h * 64;
  const u16* Vg = Vt + (size_t)bh * 64 * 2048;
  // 64-col tile staging: 8 rows/issue, chunk swizzle key = row&7
  const int sr8 = lane >> 3, sc8 = (((lane & 7) ^ sr8) << 3);
  const int fr = lane & 15, quad = lane >> 4, c0 = fr;
  const int wmS = (wave >> 1) * 32, wnS = (wave & 1) * 64;  // S^T: kv x q
  const int wmO = (wave >> 1) * 64, wnO = (wave & 1) * 32;  // O: q x d
  const int sq = t >> 1, sh = t & 1;                        // softmax role
  // stage Q once (16 issues of 8 rows)
#pragma unroll
  for (int ii = 0; ii < 4; ++ii) {
    const int i = ii * 4 + wave;
    gld_lds16(Qg + (size_t)(i * 8 + sr8) * 3072 + sc8, Qs + i * 512);
  }
  f32x4 o[4][2];
  const f32x4 z4 = {0.f, 0.f, 0.f, 0.f};
#pragma unroll
  for (int m = 0; m < 4; ++m) {
    o[m][0] = z4;
    o[m][1] = z4;
  }
  float m_run = -1e30f, l_run = 0.0f;
  for (int kv0 = 0; kv0 < 2048; kv0 += 64) {
#pragma unroll
    for (int ii = 0; ii < 2; ++ii) {
      const int i = ii * 4 + wave;
      gld_lds16(Kg + (size_t)(kv0 + i * 8 + sr8) * 3072 + sc8, Ks + i * 512);
      gld_lds16(Vg + (size_t)(i * 8 + sr8) * 2048 + kv0 + sc8, Vs + i * 512);
    }
    __syncthreads();
    // S^T = K.Q^T : m=kv (2 tiles), n=q (4 tiles), k=d (2 iters)
    f32x4 s[2][4];
#pragma unroll
    for (int m = 0; m < 2; ++m)
#pragma unroll
      for (int n = 0; n < 4; ++n) s[m][n] = z4;
#pragma unroll
    for (int kk = 0; kk < 2; ++kk) {
      bf16x8 ka[2], qb[4];
#pragma unroll
      for (int m = 0; m < 2; ++m) {
        const int row = wmS + m * 16 + fr;
        ka[m] = *(const bf16x8*)(Ks + row * 64 + ((((kk << 2) + quad) ^ (row & 7)) << 3));
      }
#pragma unroll
      for (int n = 0; n < 4; ++n) {
        const int row = wnS + n * 16 + fr;
        qb[n] = *(const bf16x8*)(Qs + row * 64 + ((((kk << 2) + quad) ^ (row & 7)) << 3));
      }
#pragma unroll
      for (int m = 0; m < 2; ++m)
#pragma unroll
        for (int n = 0; n < 4; ++n)
          s[m][n] = __builtin_amdgcn_mfma_f32_16x16x32_bf16(ka[m], qb[n], s[m][n], 0, 0, 0);
    }
    // scaled scores -> Ps[q][kv] (bf16, b64-packed along kv = reg dim)
#pragma unroll
    for (int m = 0; m < 2; ++m)
#pragma unroll
      for (int n = 0; n < 4; ++n) {
        const int q = wnS + n * 16 + c0;
        const int kv = wmS + m * 16 + (quad << 2);
        ushort4 pk;
        pk.x = f2b(s[m][n][0] * 0.125f);
        pk.y = f2b(s[m][n][1] * 0.125f);
        pk.z = f2b(s[m][n][2] * 0.125f);
        pk.w = f2b(s[m][n][3] * 0.125f);
        *(ushort4*)(Ps + q * 72 + kv) = pk;
      }
    __syncthreads();
    // online softmax: thread owns row sq, half sh (32 kv each)
    {
      u16* prow = Ps + sq * 72 + (sh << 5);
      uint4 pr[4];
#pragma unroll
      for (int i = 0; i < 4; ++i) pr[i] = *(const uint4*)(prow + i * 8);
      float mloc = -1e30f;
#pragma unroll
      for (int i = 0; i < 4; ++i) {
        const u16* us = (const u16*)&pr[i];
#pragma unroll
        for (int j = 0; j < 8; ++j) mloc = fmaxf(mloc, b2f(us[j]));
      }
      mloc = fmaxf(mloc, __shfl_xor(mloc, 1));
      const float mnew = fmaxf(m_run, mloc);
      const float aa = __expf(m_run - mnew);
      float sloc = 0.0f;
#pragma unroll
      for (int i = 0; i < 4; ++i) {
        u16* us = (u16*)&pr[i];
#pragma unroll
        for (int j = 0; j < 8; ++j) {
          const float pv = __expf(b2f(us[j]) - mnew);
          sloc += pv;
          us[j] = f2b(pv);
        }
      }
#pragma unroll
      for (int i = 0; i < 4; ++i) *(uint4*)(prow + i * 8) = pr[i];
      sloc += __shfl_xor(sloc, 1);
      l_run = l_run * aa + sloc;
      m_run = mnew;
      if (sh == 0) alpha_s[sq] = aa;
    }
    __syncthreads();
    // O = O*alpha + P.V : m=q (4 tiles), n=d (2 tiles), k=kv (2 iters)
#pragma unroll
    for (int m = 0; m < 4; ++m) {
      const f32x4 av = *(const f32x4*)(&alpha_s[wmO + m * 16 + (quad << 2)]);
      o[m][0] *= av;
      o[m][1] *= av;
    }
#pragma unroll
    for (int kk = 0; kk < 2; ++kk) {
      bf16x8 pa[4], vb[2];
#pragma unroll
      for (int m = 0; m < 4; ++m)
        pa[m] = *(const bf16x8*)(Ps + (wmO + m * 16 + fr) * 72 + (kk << 5) + (quad << 3));
#pragma unroll
      for (int n = 0; n < 2; ++n) {
        const int row = wnO + n * 16 + fr;
        vb[n] = *(const bf16x8*)(Vs + row * 64 + ((((kk << 2) + quad) ^ (row & 7)) << 3));
      }
#pragma unroll
      for (int m = 0; m < 4; ++m)
#pragma unroll
        for (int n = 0; n < 2; ++n)
          o[m][n] = __builtin_amdgcn_mfma_f32_16x16x32_bf16(pa[m], vb[n], o[m][n], 0, 0, 0);
    }
    __syncthreads();
  }
  if (sh == 0) linv_s[sq] = 1.0f / l_run;
  __syncthreads();
  u16* Og = O + ((size_t)(b * 2048 + q0)) * 1024 + h * 64;
#pragma unroll
  for (int m = 0; m < 4; ++m) {
    const f32x4 lv = *(const f32x4*)(&linv_s[wmO + m * 16 + (quad << 2)]);
#pragma unroll
    for (int n = 0; n < 2; ++n) {
      const int d = wnO + n * 16 + c0;
#pragma unroll
      for (int r = 0; r < 4; ++r) {
        const int q = wmO + m * 16 + (quad << 2) + r;
        Og[(size_t)q * 1024 + d] = f2b(o[m][n][r] * lv[r]);
      }
    }
  }
}

// Expert GEMM1 (block-table grid): Xg x W1t[e]^T, gelu -> H1 (bf16).
__global__ __launch_bounds__(256) void moe_gemm1_k(
    const u16* __restrict__ Xg, const u16* __restrict__ W1t,
    const float* __restrict__ b1, const int* __restrict__ counts,
    const int* __restrict__ offs, const int* __restrict__ blk_e,
    const int* __restrict__ blk_m, const int* __restrict__ nblk,
    u16* __restrict__ H1) {
  __shared__ __align__(16) u16 As[128 * 32];
  __shared__ __align__(16) u16 Bs[128 * 32];
  const int by = blockIdx.y;
  if (by >= *nblk) return;
  const int e = blk_e[by], m_base = blk_m[by];
  const int off_e = offs[e];
  const long n_base = (long)blockIdx.x << 7;
  const u16* A = Xg + (size_t)(off_e + m_base) * 1024;
  const u16* B = W1t + (size_t)e * 4096 * 1024 + n_base * 1024;
  f32x4 acc[4][4];
  const f32x4 z4 = {0.f, 0.f, 0.f, 0.f};
#pragma unroll
  for (int m = 0; m < 4; ++m)
#pragma unroll
    for (int n = 0; n < 4; ++n) acc[m][n] = z4;
  gemm_core<4, 4>(A, 1024, B, 1024, 1024, As, Bs, acc);
  const int M_rem = counts[e] - m_base;
  const int lane = threadIdx.x & 63, wave = threadIdx.x >> 6;
  const int wm = (wave >> 1) << 6, wn = (wave & 1) << 6;
  const int r0 = wm + ((lane >> 4) << 2), c0 = lane & 15;
  const float* b1e = b1 + (size_t)e * 4096;
#pragma unroll
  for (int n = 0; n < 4; ++n) {
    const long gn = n_base + wn + n * 16 + c0;
    const float bv = b1e[gn];
#pragma unroll
    for (int m = 0; m < 4; ++m)
#pragma unroll
      for (int r = 0; r < 4; ++r) {
        const int ml = r0 + m * 16 + r;
        if (ml >= M_rem) continue;
        H1[(size_t)(off_e + m_base + ml) * 4096 + gn] = f2b(gelu_tanh(acc[m][n][r] + bv));
      }
  }
}

// Expert GEMM2 (block-table grid): H1 x W2t[e]^T -> Ye (fp32 per slot).
__global__ __launch_bounds__(256) void moe_gemm2_k(
    const u16* __restrict__ H1, const u16* __restrict__ W2t,
    const int* __restrict__ counts, const int* __restrict__ offs,
    const int* __restrict__ blk_e, const int* __restrict__ blk_m,
    const int* __restrict__ nblk, float* __restrict__ Ye) {
  __shared__ __align__(16) u16 As[128 * 32];
  __shared__ __align__(16) u16 Bs[128 * 32];
  const int by = blockIdx.y;
  if (by >= *nblk) return;
  const int e = blk_e[by], m_base = blk_m[by];
  const int off_e = offs[e];
  const long n_base = (long)blockIdx.x << 7;
  const u16* A = H1 + (size_t)(off_e + m_base) * 4096;
  const u16* B = W2t + (size_t)e * 1024 * 4096 + n_base * 4096;
  f32x4 acc[4][4];
  const f32x4 z4 = {0.f, 0.f, 0.f, 0.f};
#pragma unroll
  for (int m = 0; m < 4; ++m)
#pragma unroll
    for (int n = 0; n < 4; ++n) acc[m][n] = z4;
  gemm_core<4, 4>(A, 4096, B, 4096, 4096, As, Bs, acc);
  const int M_rem = counts[e] - m_base;
  const int lane = threadIdx.x & 63, wave = threadIdx.x >> 6;
  const int wm = (wave >> 1) << 6, wn = (wave & 1) << 6;
  const int r0 = wm + ((lane >> 4) << 2), c0 = lane & 15;
#pragma unroll
  for (int m = 0; m < 4; ++m)
#pragma unroll
    for (int r = 0; r < 4; ++r) {
      const int ml = r0 + m * 16 + r;
      if (ml >= M_rem) continue;
      float* yrow = Ye + (size_t)(off_e + m_base + ml) * 1024 + n_base;
#pragma unroll
      for (int n = 0; n < 4; ++n) yrow[wn + n * 16 + c0] = acc[m][n][r];
    }
}

__global__ __launch_bounds__(256) void ln_k(const float* __restrict__ X,
                                            const float* __restrict__ g,
                                            const float* __restrict__ b,
                                            u16* __restrict__ Y,
                                            float2* __restrict__ stats) {
  const int row = blockIdx.x;
  const float4 xv = ((const float4*)(X + (size_t)row * 1024))[threadIdx.x];
  float s = xv.x + xv.y + xv.z + xv.w;
  float s2 = xv.x * xv.x + xv.y * xv.y + xv.z * xv.z + xv.w * xv.w;
  s = wave_sum(s);
  s2 = wave_sum(s2);
  __shared__ float rs_[4], r2_[4];
  const int lane = threadIdx.x & 63, wave = threadIdx.x >> 6;
  if (lane == 0) { rs_[wave] = s; r2_[wave] = s2; }
  __syncthreads();
  const float tot = rs_[0] + rs_[1] + rs_[2] + rs_[3];
  const float tot2 = r2_[0] + r2_[1] + r2_[2] + r2_[3];
  const float mu = tot * (1.0f / 1024.0f);
  const float var = tot2 * (1.0f / 1024.0f) - mu * mu;
  const float rstd = rsqrtf(var + 1e-5f);
  const float4 gv = ((const float4*)g)[threadIdx.x];
  const float4 bv = ((const float4*)b)[threadIdx.x];
  ushort4 o;
  o.x = f2b((xv.x - mu) * rstd * gv.x + bv.x);
  o.y = f2b((xv.y - mu) * rstd * gv.y + bv.y);
  o.z = f2b((xv.z - mu) * rstd * gv.z + bv.z);
  o.w = f2b((xv.w - mu) * rstd * gv.w + bv.w);
  ((ushort4*)(Y + (size_t)row * 1024))[threadIdx.x] = o;
  if (stats != nullptr && threadIdx.x == 0) stats[row] = make_float2(mu, rstd);
}

__global__ __launch_bounds__(256) void logits_k(
    const float* __restrict__ X2, const float2* __restrict__ stats,
    const float* __restrict__ g, const float* __restrict__ b,
    const float* __restrict__ Wg, float* __restrict__ logits) {
  const int row = blockIdx.x;
  const float2 st = stats[row];
  const float4 xv = ((const float4*)(X2 + (size_t)row * 1024))[threadIdx.x];
  const float4 gv = ((const float4*)g)[threadIdx.x];
  const float4 bv = ((const float4*)b)[threadIdx.x];
  float xt[4];
  xt[0] = (xv.x - st.x) * st.y * gv.x + bv.x;
  xt[1] = (xv.y - st.x) * st.y * gv.y + bv.y;
  xt[2] = (xv.z - st.x) * st.y * gv.z + bv.z;
  xt[3] = (xv.w - st.x) * st.y * gv.w + bv.w;
  float acc[8] = {0, 0, 0, 0, 0, 0, 0, 0};
  const float* w = Wg + (size_t)(threadIdx.x << 2) * 8;
#pragma unroll
  for (int j = 0; j < 4; ++j)
#pragma unroll
    for (int e = 0; e < 8; ++e) acc[e] += xt[j] * w[j * 8 + e];
#pragma unroll
  for (int e = 0; e < 8; ++e) acc[e] = wave_sum(acc[e]);
  __shared__ float red[4][8];
  const int lane = threadIdx.x & 63, wave = threadIdx.x >> 6;
  if (lane == 0) {
#pragma unroll
    for (int e = 0; e < 8; ++e) red[wave][e] = acc[e];
  }
  __syncthreads();
  if (threadIdx.x < 8)
    logits[(size_t)row * 8 + threadIdx.x] = red[0][threadIdx.x] +
        red[1][threadIdx.x] + red[2][threadIdx.x] + red[3][threadIdx.x];
}

__global__ void top2_k(const float* __restrict__ logits, int* __restrict__ topi,
                       float* __restrict__ gatew, int* __restrict__ counts) {
  const int t = blockIdx.x * 256 + threadIdx.x;
  if (t >= 4096) return;
  float l[8];
#pragma unroll
  for (int e = 0; e < 8; ++e) l[e] = logits[(size_t)t * 8 + e];
  int i0 = 0;
  float v0 = l[0];
#pragma unroll
  for (int e = 1; e < 8; ++e)
    if (l[e] > v0) { v0 = l[e]; i0 = e; }
  int i1 = -1;
  float v1 = -1e30f;
#pragma unroll
  for (int e = 0; e < 8; ++e)
    if (e != i0 && l[e] > v1) { v1 = l[e]; i1 = e; }
  const float g0 = 1.0f / (1.0f + __expf(v1 - v0));
  topi[2 * t] = i0;
  topi[2 * t + 1] = i1;
  gatew[2 * t] = g0;
  gatew[2 * t + 1] = 1.0f - g0;
  atomicAdd(&counts[i0], 1);
  atomicAdd(&counts[i1], 1);
}

// Also builds the compacted (expert, m_base) block table (<=71 entries).
__global__ void offsets_k(const int* __restrict__ counts, int* __restrict__ offs,
                          int* __restrict__ cursors, int* __restrict__ blk_e,
                          int* __restrict__ blk_m, int* __restrict__ nblk) {
  if (threadIdx.x == 0) {
    int s = 0, nb = 0;
    for (int e = 0; e < 8; ++e) {
      offs[e] = s;
      for (int mb = 0; mb < counts[e]; mb += 128) {
        blk_e[nb] = e;
        blk_m[nb] = mb;
        ++nb;
      }
      s += counts[e];
    }
    *nblk = nb;
  }
  if (threadIdx.x < 8) cursors[threadIdx.x] = 0;
}

__global__ void route_k(const int* __restrict__ topi,
                        const int* __restrict__ offs, int* __restrict__ cursors,
                        int* __restrict__ token_ids, int* __restrict__ tok2slot) {
  const int i = blockIdx.x * 256 + threadIdx.x;
  if (i >= 8192) return;
  const int t = i >> 1;
  const int e = topi[i];
  const int pos = offs[e] + atomicAdd(&cursors[e], 1);
  token_ids[pos] = t;
  tok2slot[i] = pos;
}

__global__ void gather_k(const u16* __restrict__ X,
                         const int* __restrict__ token_ids,
                         u16* __restrict__ Xg) {
  const int i = blockIdx.x * 256 + threadIdx.x;
  const int slot = i >> 7, c = i & 127;
  ((uint4*)Xg)[(size_t)slot * 128 + c] =
      ((const uint4*)X)[(size_t)token_ids[slot] * 128 + c];
}

__global__ void combine_k(const float* __restrict__ X2,
                          const int* __restrict__ topi,
                          const float* __restrict__ gatew,
                          const int* __restrict__ tok2slot,
                          const float* __restrict__ Ye,
                          const float* __restrict__ b2,
                          float* __restrict__ Out) {
  const int t = blockIdx.x;
  float4 v = ((const float4*)(X2 + (size_t)t * 1024))[threadIdx.x];
  const int e0 = topi[2 * t], e1 = topi[2 * t + 1];
  const float g0 = gatew[2 * t], g1 = gatew[2 * t + 1];
  const int s0 = tok2slot[2 * t], s1 = tok2slot[2 * t + 1];
  const float4 y0 = ((const float4*)(Ye + (size_t)s0 * 1024))[threadIdx.x];
  const float4 y1 = ((const float4*)(Ye + (size_t)s1 * 1024))[threadIdx.x];
  const float4 c0 = ((const float4*)(b2 + (size_t)e0 * 1024))[threadIdx.x];
  const float4 c1 = ((const float4*)(b2 + (size_t)e1 * 1024))[threadIdx.x];
  v.x += g0 * (y0.x + c0.x) + g1 * (y1.x + c1.x);
  v.y += g0 * (y0.y + c0.y) + g1 * (y1.y + c1.y);
  v.z += g0 * (y0.z + c0.z) + g1 * (y1.z + c1.z);
  v.w += g0 * (y0.w + c0.w) + g1 * (y1.w + c1.w);
  ((float4*)(Out + (size_t)t * 1024))[threadIdx.x] = v;
}

__global__ void cvt_k(const float* __restrict__ in, u16* __restrict__ out, int n4) {
  const int i = blockIdx.x * 256 + threadIdx.x;
  if (i >= n4) return;
  const float4 v = ((const float4*)in)[i];
  ushort4 o;
  o.x = f2b(v.x);
  o.y = f2b(v.y);
  o.z = f2b(v.z);
  o.w = f2b(v.w);
  ((ushort4*)out)[i] = o;
}

__global__ __launch_bounds__(256) void transpose_cvt_k(
    const float* __restrict__ in, u16* __restrict__ out, int R, int C) {
  __shared__ float tile[32][33];
  const size_t eo = (size_t)blockIdx.z * (size_t)R * C;
  in += eo;
  out += eo;
  const int cb = blockIdx.x << 5, rb = blockIdx.y << 5;
  const int tx = threadIdx.x & 31, ty = threadIdx.x >> 5;
#pragma unroll
  for (int i = 0; i < 4; ++i)
    tile[ty + i * 8][tx] = in[(size_t)(rb + ty + i * 8) * C + cb + tx];
  __syncthreads();
#pragma unroll
  for (int i = 0; i < 4; ++i)
    out[(size_t)(cb + ty + i * 8) * R + rb + tx] = f2b(tile[tx][ty + i * 8]);
}

// V columns of qkv [T,3072] -> Vt[bh][64,2048] bf16
__global__ __launch_bounds__(256) void vtrans_k(const u16* __restrict__ qkv,
                                                u16* __restrict__ Vt) {
  __shared__ u16 tile[32][33];
  const int z = blockIdx.z, b = z >> 4, h = z & 15;
  const int sb = blockIdx.x << 5;
  const int db = blockIdx.y << 5;
  const int tx = threadIdx.x & 31, ty = threadIdx.x >> 5;
  const u16* src = qkv + ((size_t)b * 2048) * 3072 + 2048 + h * 64;
#pragma unroll
  for (int i = 0; i < 4; ++i)
    tile[ty + i * 8][tx] = src[(size_t)(sb + ty + i * 8) * 3072 + db + tx];
  __syncthreads();
  u16* dst = Vt + ((size_t)z * 64 + db) * 2048 + sb;
#pragma unroll
  for (int i = 0; i < 4; ++i)
    dst[(size_t)(ty + i * 8) * 2048 + tx] = tile[tx][ty + i * 8];
}

__global__ void zero_k(int* __restrict__ counts) {
  if (threadIdx.x < 8) counts[threadIdx.x] = 0;
}

extern "C" void kernel_launch(void* const* d_in, const int* in_sizes, int n_in,
                              void* d_out, int out_size, void* d_ws,
                              size_t ws_size, hipStream_t stream) {
  (void)in_sizes; (void)n_in; (void)out_size;
  const float* x = (const float*)d_in[0];
  const float* ln1_g = (const float*)d_in[1];
  const float* ln1_b = (const float*)d_in[2];
  const float* qkv_w = (const float*)d_in[3];
  const float* qkv_b = (const float*)d_in[4];
  const float* out_w = (const float*)d_in[5];
  const float* out_b = (const float*)d_in[6];
  const float* ln2_g = (const float*)d_in[7];
  const float* ln2_b = (const float*)d_in[8];
  const float* Wg = (const float*)d_in[9];
  const float* W1 = (const float*)d_in[10];
  const float* b1 = (const float*)d_in[11];
  const float* W2 = (const float*)d_in[12];
  const float* b2 = (const float*)d_in[13];
  float* out = (float*)d_out;

  const int T = 4096, H = 1024, F = 4096, E = 8;

  char* p = (char*)d_ws;
  auto alloc = [&](size_t n) {
    char* r = p;
    p += (n + 255) & ~(size_t)255;
    return r;
  };
  u16* qkvw_bf = (u16*)alloc((size_t)3 * H * H * 2);
  u16* outw_bf = (u16*)alloc((size_t)H * H * 2);
  u16* W1t = (u16*)alloc((size_t)E * F * H * 2);
  u16* W2t = (u16*)alloc((size_t)E * H * F * 2);
  u16* h1bf = (u16*)alloc((size_t)T * H * 2);    // reused as Vt after QKV
  u16* qkvbf = (u16*)alloc((size_t)T * 3 * H * 2);
  u16* obf = (u16*)alloc((size_t)T * H * 2);     // reused as h2bf
  float* x2 = (float*)alloc((size_t)T * H * 4);
  u16* H1 = (u16*)alloc((size_t)(2 * T + 128) * F * 2);
  float* Ye = (float*)alloc((size_t)2 * T * H * 4);
  u16* Xg = (u16*)alloc((size_t)(2 * T + 128) * H * 2);
  float* logits = (float*)alloc((size_t)T * E * 4);
  float2* stats = (float2*)alloc((size_t)T * 8);
  int* topi = (int*)alloc((size_t)T * 2 * 4);
  float* gatew = (float*)alloc((size_t)T * 2 * 4);
  int* counts = (int*)alloc(64);
  int* offs = (int*)alloc(64);
  int* cursors = (int*)alloc(64);
  int* blk_e = (int*)alloc(512);
  int* blk_m = (int*)alloc(512);
  int* nblk = (int*)alloc(64);
  int* token_ids = (int*)alloc((size_t)(2 * T + 128) * 4);
  int* tok2slot = (int*)alloc((size_t)2 * T * 4);
  if ((size_t)(p - (char*)d_ws) > ws_size) return;

  u16* Vt = h1bf;
  u16* h2bf = obf;

  zero_k<<<1, 64, 0, stream>>>(counts);
  cvt_k<<<3 * H * H / 4 / 256, 256, 0, stream>>>(qkv_w, qkvw_bf, 3 * H * H / 4);
  cvt_k<<<H * H / 4 / 256, 256, 0, stream>>>(out_w, outw_bf, H * H / 4);
  transpose_cvt_k<<<dim3(F / 32, H / 32, E), 256, 0, stream>>>(W1, W1t, H, F);
  transpose_cvt_k<<<dim3(H / 32, F / 32, E), 256, 0, stream>>>(W2, W2t, F, H);

  ln_k<<<T, 256, 0, stream>>>(x, ln1_g, ln1_b, h1bf, nullptr);

  gemm_k<EP_BF16, 4, 4><<<dim3(3 * H / 128, T / 128), 256, 0, stream>>>(
      h1bf, H, qkvw_bf, H, qkv_b, 1.0f, nullptr, qkvbf, 3 * H, nullptr, H);

  vtrans_k<<<dim3(2048 / 32, 2, 32), 256, 0, stream>>>(qkvbf, Vt);

  flash_attn_k<<<dim3(2048 / 128, 32), 256, 0, stream>>>(qkvbf, Vt, obf);

  gemm_k<EP_F32RES, 4, 4><<<dim3(H / 128, T / 128), 256, 0, stream>>>(
      obf, H, outw_bf, H, out_b, 1.0f, x2, nullptr, H, x, H);

  ln_k<<<T, 256, 0, stream>>>(x2, ln2_g, ln2_b, h2bf, stats);
  logits_k<<<T, 256, 0, stream>>>(x2, stats, ln2_g, ln2_b, Wg, logits);
  top2_k<<<T / 256, 256, 0, stream>>>(logits, topi, gatew, counts);
  offsets_k<<<1, 64, 0, stream>>>(counts, offs, cursors, blk_e, blk_m, nblk);
  route_k<<<2 * T / 256, 256, 0, stream>>>(topi, offs, cursors, token_ids,
                                           tok2slot);
  gather_k<<<2 * T * (H / 8) / 256, 256, 0, stream>>>(h2bf, token_ids, Xg);

  moe_gemm1_k<<<dim3(F / 128, 72), 256, 0, stream>>>(Xg, W1t, b1, counts, offs,
                                                     blk_e, blk_m, nblk, H1);
  moe_gemm2_k<<<dim3(H / 128, 72), 256, 0, stream>>>(H1, W2t, counts, offs,
                                                     blk_e, blk_m, nblk, Ye);

  combine_k<<<T, 256, 0, stream>>>(x2, topi, gatew, tok2slot, Ye, b2, out);
}

// Round 4
// 966.024 us; speedup vs baseline: 1.4152x; 1.0273x over previous
//
#include <hip/hip_runtime.h>
#include <hip/hip_bf16.h>

typedef unsigned short u16;
typedef __bf16 bf16x8 __attribute__((ext_vector_type(8)));
typedef float f32x4 __attribute__((ext_vector_type(4)));
typedef __attribute__((address_space(3))) unsigned lds_u32;
typedef __attribute__((address_space(1))) const unsigned gbl_u32;

#define DI __device__ __forceinline__

DI u16 f2b(float f) {
  unsigned u = __builtin_bit_cast(unsigned, f);
  unsigned r = (u + 0x7FFFu + ((u >> 16) & 1u)) >> 16;
  return (u16)r;
}
DI float b2f(u16 h) {
  unsigned u = ((unsigned)h) << 16;
  return __builtin_bit_cast(float, u);
}
DI float wave_sum(float v) {
#pragma unroll
  for (int o = 32; o > 0; o >>= 1) v += __shfl_down(v, o);
  return v;
}
DI float gelu_tanh(float v) {
  float u = 0.7978845608028654f * (v + 0.044715f * v * v * v);
  float eu = __expf(-2.0f * fabsf(u));
  float th = (1.0f - eu) / (1.0f + eu);
  th = (u < 0.0f) ? -th : th;
  return 0.5f * v * (1.0f + th);
}

// Async global->LDS, 16B per lane. LDS dest is wave-uniform base + lane*16.
DI void gld_lds16(const u16* g, u16* l) {
  __builtin_amdgcn_global_load_lds((gbl_u32*)g, (lds_u32*)l, 16, 0, 0);
}

// ---------------------------------------------------------------------------
// m97-class GEMM core, BK=32, LDS row stride 32 elem (64B) contiguous.
// XOR swizzle (r3: verified kills all bank conflicts): lane stages global
// chunk (lane&3)^((lane>>3)&3); fragment reads apply the matching XOR.
// ---------------------------------------------------------------------------
template <int MT, int NT>
DI void gemm_core(const u16* __restrict__ A, long lda, const u16* __restrict__ B,
                  long ldb, int K, u16* As, u16* Bs, f32x4 acc[MT][NT]) {
  const int t = threadIdx.x, lane = t & 63, wave = t >> 6;
  const int wm = (wave >> 1) * (MT * 16), wn = (wave & 1) * (NT * 16);
  const int sr = lane >> 2;
  const int sc = (((lane & 3) ^ ((lane >> 3) & 3)) << 3);
  const int fr = lane & 15;
  const int fk = ((((lane >> 4) ^ ((fr >> 1) & 3))) << 3);
  for (int kb = 0; kb < K; kb += 32) {
#pragma unroll
    for (int ii = 0; ii < MT / 2; ++ii) {
      const int i = ii * 4 + wave;
      gld_lds16(A + (size_t)(i * 16 + sr) * lda + kb + sc, As + i * 512);
    }
#pragma unroll
    for (int ii = 0; ii < NT / 2; ++ii) {
      const int i = ii * 4 + wave;
      gld_lds16(B + (size_t)(i * 16 + sr) * ldb + kb + sc, Bs + i * 512);
    }
    __syncthreads();
    bf16x8 af[MT], bfr[NT];
#pragma unroll
    for (int m = 0; m < MT; ++m)
      af[m] = *(const bf16x8*)(As + (wm + m * 16 + fr) * 32 + fk);
#pragma unroll
    for (int n = 0; n < NT; ++n)
      bfr[n] = *(const bf16x8*)(Bs + (wn + n * 16 + fr) * 32 + fk);
#pragma unroll
    for (int m = 0; m < MT; ++m)
#pragma unroll
      for (int n = 0; n < NT; ++n)
        acc[m][n] =
            __builtin_amdgcn_mfma_f32_16x16x32_bf16(af[m], bfr[n], acc[m][n], 0, 0, 0);
    __syncthreads();
  }
}

// Plain GEMM, bf16 output with bias (QKV).
template <int MT, int NT>
__global__ __launch_bounds__(256) void gemm_k(
    const u16* __restrict__ A, long lda, const u16* __restrict__ B, long ldb,
    const float* __restrict__ bias, u16* __restrict__ Cb, long ldc, int K) {
  constexpr int BM = MT * 32, BN = NT * 32;
  __shared__ __align__(16) u16 As[BM * 32];
  __shared__ __align__(16) u16 Bs[BN * 32];
  const long m_base = (long)blockIdx.y * BM, n_base = (long)blockIdx.x * BN;
  f32x4 acc[MT][NT];
  const f32x4 z4 = {0.f, 0.f, 0.f, 0.f};
#pragma unroll
  for (int m = 0; m < MT; ++m)
#pragma unroll
    for (int n = 0; n < NT; ++n) acc[m][n] = z4;
  gemm_core<MT, NT>(A + m_base * lda, lda, B + n_base * ldb, ldb, K, As, Bs, acc);
  const int lane = threadIdx.x & 63, wave = threadIdx.x >> 6;
  const int wm = (wave >> 1) * (MT * 16), wn = (wave & 1) * (NT * 16);
  const int r0 = wm + ((lane >> 4) << 2), c0 = lane & 15;
#pragma unroll
  for (int n = 0; n < NT; ++n) {
    const long gn = n_base + wn + n * 16 + c0;
    const float bv = bias[gn];
#pragma unroll
    for (int m = 0; m < MT; ++m)
#pragma unroll
      for (int r = 0; r < 4; ++r) {
        const long gm = m_base + r0 + m * 16 + r;
        Cb[gm * ldc + gn] = f2b(acc[m][n][r] + bv);
      }
  }
}

// Split-K GEMM: z = kz, each handles K_per cols of K, writes fp32 partial
// Cp[kz][M][N] (no bias). Used by out-proj.
template <int MT, int NT>
__global__ __launch_bounds__(256) void gemm_pk_k(
    const u16* __restrict__ A, long lda, const u16* __restrict__ B, long ldb,
    float* __restrict__ Cp, long M, long N, int K_per) {
  constexpr int BM = MT * 32, BN = NT * 32;
  __shared__ __align__(16) u16 As[BM * 32];
  __shared__ __align__(16) u16 Bs[BN * 32];
  const long m_base = (long)blockIdx.y * BM, n_base = (long)blockIdx.x * BN;
  const long k0 = (long)blockIdx.z * K_per;
  f32x4 acc[MT][NT];
  const f32x4 z4 = {0.f, 0.f, 0.f, 0.f};
#pragma unroll
  for (int m = 0; m < MT; ++m)
#pragma unroll
    for (int n = 0; n < NT; ++n) acc[m][n] = z4;
  gemm_core<MT, NT>(A + m_base * lda + k0, lda, B + n_base * ldb + k0, ldb,
                    K_per, As, Bs, acc);
  float* C = Cp + (size_t)blockIdx.z * M * N;
  const int lane = threadIdx.x & 63, wave = threadIdx.x >> 6;
  const int wm = (wave >> 1) * (MT * 16), wn = (wave & 1) * (NT * 16);
  const int r0 = wm + ((lane >> 4) << 2), c0 = lane & 15;
#pragma unroll
  for (int m = 0; m < MT; ++m)
#pragma unroll
    for (int r = 0; r < 4; ++r) {
      const long gm = m_base + r0 + m * 16 + r;
      float* crow = C + gm * N + n_base;
#pragma unroll
      for (int n = 0; n < NT; ++n) crow[wn + n * 16 + c0] = acc[m][n][r];
    }
}

// x2 = P0 + P1 + bias + resid
__global__ void reduce2_k(const float* __restrict__ P0,
                          const float* __restrict__ P1,
                          const float* __restrict__ bias,
                          const float* __restrict__ resid,
                          float* __restrict__ X2) {
  const size_t row = blockIdx.x;
  const int c = threadIdx.x;
  const float4 a = ((const float4*)(P0 + row * 1024))[c];
  const float4 b = ((const float4*)(P1 + row * 1024))[c];
  const float4 bb = ((const float4*)bias)[c];
  const float4 rr = ((const float4*)(resid + row * 1024))[c];
  float4 v;
  v.x = a.x + b.x + bb.x + rr.x;
  v.y = a.y + b.y + bb.y + rr.y;
  v.z = a.z + b.z + bb.z + rr.z;
  v.w = a.w + b.w + bb.w + rr.w;
  ((float4*)(X2 + row * 1024))[c] = v;
}

// ---------------------------------------------------------------------------
// Flash attention, Q-tile 64, KV-tile 64, D=64. Grid (S/64, B*NH) = 1024
// blocks; LDS ~34 KB -> 4 blocks/CU (TLP > per-block MFMA density here).
// S computed transposed (S^T = K.Q^T); waves 2x2 (wr=kv/q-half, wc).
// ---------------------------------------------------------------------------
__global__ __launch_bounds__(256) void flash_attn_k(const u16* __restrict__ qkv,
                                                    const u16* __restrict__ Vt,
                                                    u16* __restrict__ O) {
  __shared__ __align__(16) u16 Qs[64 * 64];
  __shared__ __align__(16) u16 Ks[64 * 64];
  __shared__ __align__(16) u16 Vs[64 * 64];
  __shared__ __align__(16) u16 Ps[64 * 72];
  __shared__ __align__(16) float alpha_s[64];
  __shared__ __align__(16) float linv_s[64];
  const int t = threadIdx.x, lane = t & 63, wave = t >> 6;
  const int wr = wave >> 1, wc = wave & 1;
  const int bh = blockIdx.y, b = bh >> 4, h = bh & 15;
  const int q0 = blockIdx.x << 6;
  const u16* Qg = qkv + ((size_t)(b * 2048 + q0)) * 3072 + h * 64;
  const u16* Kg = qkv + ((size_t)b * 2048) * 3072 + 1024 + h * 64;
  const u16* Vg = Vt + (size_t)bh * 64 * 2048;
  const int sr8 = lane >> 3, sc8 = (((lane & 7) ^ sr8) << 3);
  const int fr = lane & 15, quad = lane >> 4, c0 = fr;
  const int sq = t >> 2, sh = t & 3;  // softmax: 4 threads per q-row
  // stage Q once (8 issues of 8 rows)
#pragma unroll
  for (int ii = 0; ii < 2; ++ii) {
    const int i = ii * 4 + wave;
    gld_lds16(Qg + (size_t)(i * 8 + sr8) * 3072 + sc8, Qs + i * 512);
  }
  f32x4 o[2][2];
  const f32x4 z4 = {0.f, 0.f, 0.f, 0.f};
#pragma unroll
  for (int m = 0; m < 2; ++m) {
    o[m][0] = z4;
    o[m][1] = z4;
  }
  float m_run = -1e30f, l_run = 0.0f;
  for (int kv0 = 0; kv0 < 2048; kv0 += 64) {
#pragma unroll
    for (int ii = 0; ii < 2; ++ii) {
      const int i = ii * 4 + wave;
      gld_lds16(Kg + (size_t)(kv0 + i * 8 + sr8) * 3072 + sc8, Ks + i * 512);
      gld_lds16(Vg + (size_t)(i * 8 + sr8) * 2048 + kv0 + sc8, Vs + i * 512);
    }
    __syncthreads();
    // S^T = K.Q^T : m=kv (2x16 at wr*32), n=q (2x16 at wc*32), k=d
    f32x4 s[2][2];
#pragma unroll
    for (int m = 0; m < 2; ++m)
#pragma unroll
      for (int n = 0; n < 2; ++n) s[m][n] = z4;
#pragma unroll
    for (int kk = 0; kk < 2; ++kk) {
      bf16x8 ka[2], qb[2];
#pragma unroll
      for (int m = 0; m < 2; ++m) {
        const int row = wr * 32 + m * 16 + fr;
        ka[m] = *(const bf16x8*)(Ks + row * 64 + ((((kk << 2) + quad) ^ (row & 7)) << 3));
      }
#pragma unroll
      for (int n = 0; n < 2; ++n) {
        const int row = wc * 32 + n * 16 + fr;
        qb[n] = *(const bf16x8*)(Qs + row * 64 + ((((kk << 2) + quad) ^ (row & 7)) << 3));
      }
#pragma unroll
      for (int m = 0; m < 2; ++m)
#pragma unroll
        for (int n = 0; n < 2; ++n)
          s[m][n] = __builtin_amdgcn_mfma_f32_16x16x32_bf16(ka[m], qb[n], s[m][n], 0, 0, 0);
    }
#pragma unroll
    for (int m = 0; m < 2; ++m)
#pragma unroll
      for (int n = 0; n < 2; ++n) {
        const int q = wc * 32 + n * 16 + c0;
        const int kv = wr * 32 + m * 16 + (quad << 2);
        ushort4 pk;
        pk.x = f2b(s[m][n][0] * 0.125f);
        pk.y = f2b(s[m][n][1] * 0.125f);
        pk.z = f2b(s[m][n][2] * 0.125f);
        pk.w = f2b(s[m][n][3] * 0.125f);
        *(ushort4*)(Ps + q * 72 + kv) = pk;
      }
    __syncthreads();
    // online softmax: 4 threads per q-row, 16 kv each
    {
      u16* prow = Ps + sq * 72 + (sh << 4);
      uint4 pr[2];
#pragma unroll
      for (int i = 0; i < 2; ++i) pr[i] = *(const uint4*)(prow + i * 8);
      float mloc = -1e30f;
#pragma unroll
      for (int i = 0; i < 2; ++i) {
        const u16* us = (const u16*)&pr[i];
#pragma unroll
        for (int j = 0; j < 8; ++j) mloc = fmaxf(mloc, b2f(us[j]));
      }
      mloc = fmaxf(mloc, __shfl_xor(mloc, 1));
      mloc = fmaxf(mloc, __shfl_xor(mloc, 2));
      const float mnew = fmaxf(m_run, mloc);
      const float aa = __expf(m_run - mnew);
      float sloc = 0.0f;
#pragma unroll
      for (int i = 0; i < 2; ++i) {
        u16* us = (u16*)&pr[i];
#pragma unroll
        for (int j = 0; j < 8; ++j) {
          const float pv = __expf(b2f(us[j]) - mnew);
          sloc += pv;
          us[j] = f2b(pv);
        }
      }
#pragma unroll
      for (int i = 0; i < 2; ++i) *(uint4*)(prow + i * 8) = pr[i];
      sloc += __shfl_xor(sloc, 1);
      sloc += __shfl_xor(sloc, 2);
      l_run = l_run * aa + sloc;
      m_run = mnew;
      if (sh == 0) alpha_s[sq] = aa;
    }
    __syncthreads();
    // O = O*alpha + P.V : m=q (2x16 at wr*32), n=d (2x16 at wc*32), k=kv
#pragma unroll
    for (int m = 0; m < 2; ++m) {
      const f32x4 av = *(const f32x4*)(&alpha_s[wr * 32 + m * 16 + (quad << 2)]);
      o[m][0] *= av;
      o[m][1] *= av;
    }
#pragma unroll
    for (int kk = 0; kk < 2; ++kk) {
      bf16x8 pa[2], vb[2];
#pragma unroll
      for (int m = 0; m < 2; ++m)
        pa[m] = *(const bf16x8*)(Ps + (wr * 32 + m * 16 + fr) * 72 + (kk << 5) + (quad << 3));
#pragma unroll
      for (int n = 0; n < 2; ++n) {
        const int row = wc * 32 + n * 16 + fr;
        vb[n] = *(const bf16x8*)(Vs + row * 64 + ((((kk << 2) + quad) ^ (row & 7)) << 3));
      }
#pragma unroll
      for (int m = 0; m < 2; ++m)
#pragma unroll
        for (int n = 0; n < 2; ++n)
          o[m][n] = __builtin_amdgcn_mfma_f32_16x16x32_bf16(pa[m], vb[n], o[m][n], 0, 0, 0);
    }
    __syncthreads();
  }
  if (sh == 0) linv_s[sq] = 1.0f / l_run;
  __syncthreads();
  u16* Og = O + ((size_t)(b * 2048 + q0)) * 1024 + h * 64;
#pragma unroll
  for (int m = 0; m < 2; ++m) {
    const f32x4 lv = *(const f32x4*)(&linv_s[wr * 32 + m * 16 + (quad << 2)]);
#pragma unroll
    for (int n = 0; n < 2; ++n) {
      const int d = wc * 32 + n * 16 + c0;
#pragma unroll
      for (int r = 0; r < 4; ++r) {
        const int q = wr * 32 + m * 16 + (quad << 2) + r;
        Og[(size_t)q * 1024 + d] = f2b(o[m][n][r] * lv[r]);
      }
    }
  }
}

// Expert GEMM1 (block-table grid): Xg x W1t[e]^T, gelu -> H1 (bf16).
__global__ __launch_bounds__(256) void moe_gemm1_k(
    const u16* __restrict__ Xg, const u16* __restrict__ W1t,
    const float* __restrict__ b1, const int* __restrict__ counts,
    const int* __restrict__ offs, const int* __restrict__ blk_e,
    const int* __restrict__ blk_m, const int* __restrict__ nblk,
    u16* __restrict__ H1) {
  __shared__ __align__(16) u16 As[128 * 32];
  __shared__ __align__(16) u16 Bs[128 * 32];
  const int by = blockIdx.y;
  if (by >= *nblk) return;
  const int e = blk_e[by], m_base = blk_m[by];
  const int off_e = offs[e];
  const long n_base = (long)blockIdx.x << 7;
  const u16* A = Xg + (size_t)(off_e + m_base) * 1024;
  const u16* B = W1t + (size_t)e * 4096 * 1024 + n_base * 1024;
  f32x4 acc[4][4];
  const f32x4 z4 = {0.f, 0.f, 0.f, 0.f};
#pragma unroll
  for (int m = 0; m < 4; ++m)
#pragma unroll
    for (int n = 0; n < 4; ++n) acc[m][n] = z4;
  gemm_core<4, 4>(A, 1024, B, 1024, 1024, As, Bs, acc);
  const int M_rem = counts[e] - m_base;
  const int lane = threadIdx.x & 63, wave = threadIdx.x >> 6;
  const int wm = (wave >> 1) << 6, wn = (wave & 1) << 6;
  const int r0 = wm + ((lane >> 4) << 2), c0 = lane & 15;
  const float* b1e = b1 + (size_t)e * 4096;
#pragma unroll
  for (int n = 0; n < 4; ++n) {
    const long gn = n_base + wn + n * 16 + c0;
    const float bv = b1e[gn];
#pragma unroll
    for (int m = 0; m < 4; ++m)
#pragma unroll
      for (int r = 0; r < 4; ++r) {
        const int ml = r0 + m * 16 + r;
        if (ml >= M_rem) continue;
        H1[(size_t)(off_e + m_base + ml) * 4096 + gn] = f2b(gelu_tanh(acc[m][n][r] + bv));
      }
  }
}

// Expert GEMM2, split-K (z=kz of 2): H1 x W2t[e]^T -> Yp[kz] (fp32 partial).
__global__ __launch_bounds__(256) void moe_gemm2_k(
    const u16* __restrict__ H1, const u16* __restrict__ W2t,
    const int* __restrict__ counts, const int* __restrict__ offs,
    const int* __restrict__ blk_e, const int* __restrict__ blk_m,
    const int* __restrict__ nblk, float* __restrict__ Yp0,
    float* __restrict__ Yp1) {
  __shared__ __align__(16) u16 As[128 * 32];
  __shared__ __align__(16) u16 Bs[128 * 32];
  const int by = blockIdx.y;
  if (by >= *nblk) return;
  const int e = blk_e[by], m_base = blk_m[by];
  const int off_e = offs[e];
  const long n_base = (long)blockIdx.x << 7;
  const int kz = blockIdx.z;
  const long k0 = (long)kz * 2048;
  const u16* A = H1 + (size_t)(off_e + m_base) * 4096 + k0;
  const u16* B = W2t + (size_t)e * 1024 * 4096 + n_base * 4096 + k0;
  f32x4 acc[4][4];
  const f32x4 z4 = {0.f, 0.f, 0.f, 0.f};
#pragma unroll
  for (int m = 0; m < 4; ++m)
#pragma unroll
    for (int n = 0; n < 4; ++n) acc[m][n] = z4;
  gemm_core<4, 4>(A, 4096, B, 4096, 2048, As, Bs, acc);
  float* Yp = kz ? Yp1 : Yp0;
  const int M_rem = counts[e] - m_base;
  const int lane = threadIdx.x & 63, wave = threadIdx.x >> 6;
  const int wm = (wave >> 1) << 6, wn = (wave & 1) << 6;
  const int r0 = wm + ((lane >> 4) << 2), c0 = lane & 15;
#pragma unroll
  for (int m = 0; m < 4; ++m)
#pragma unroll
    for (int r = 0; r < 4; ++r) {
      const int ml = r0 + m * 16 + r;
      if (ml >= M_rem) continue;
      float* yrow = Yp + (size_t)(off_e + m_base + ml) * 1024 + n_base;
#pragma unroll
      for (int n = 0; n < 4; ++n) yrow[wn + n * 16 + c0] = acc[m][n][r];
    }
}

__global__ __launch_bounds__(256) void ln_k(const float* __restrict__ X,
                                            const float* __restrict__ g,
                                            const float* __restrict__ b,
                                            u16* __restrict__ Y,
                                            float2* __restrict__ stats) {
  const int row = blockIdx.x;
  const float4 xv = ((const float4*)(X + (size_t)row * 1024))[threadIdx.x];
  float s = xv.x + xv.y + xv.z + xv.w;
  float s2 = xv.x * xv.x + xv.y * xv.y + xv.z * xv.z + xv.w * xv.w;
  s = wave_sum(s);
  s2 = wave_sum(s2);
  __shared__ float rs_[4], r2_[4];
  const int lane = threadIdx.x & 63, wave = threadIdx.x >> 6;
  if (lane == 0) { rs_[wave] = s; r2_[wave] = s2; }
  __syncthreads();
  const float tot = rs_[0] + rs_[1] + rs_[2] + rs_[3];
  const float tot2 = r2_[0] + r2_[1] + r2_[2] + r2_[3];
  const float mu = tot * (1.0f / 1024.0f);
  const float var = tot2 * (1.0f / 1024.0f) - mu * mu;
  const float rstd = rsqrtf(var + 1e-5f);
  const float4 gv = ((const float4*)g)[threadIdx.x];
  const float4 bv = ((const float4*)b)[threadIdx.x];
  ushort4 o;
  o.x = f2b((xv.x - mu) * rstd * gv.x + bv.x);
  o.y = f2b((xv.y - mu) * rstd * gv.y + bv.y);
  o.z = f2b((xv.z - mu) * rstd * gv.z + bv.z);
  o.w = f2b((xv.w - mu) * rstd * gv.w + bv.w);
  ((ushort4*)(Y + (size_t)row * 1024))[threadIdx.x] = o;
  if (stats != nullptr && threadIdx.x == 0) stats[row] = make_float2(mu, rstd);
}

__global__ __launch_bounds__(256) void logits_k(
    const float* __restrict__ X2, const float2* __restrict__ stats,
    const float* __restrict__ g, const float* __restrict__ b,
    const float* __restrict__ Wg, float* __restrict__ logits) {
  const int row = blockIdx.x;
  const float2 st = stats[row];
  const float4 xv = ((const float4*)(X2 + (size_t)row * 1024))[threadIdx.x];
  const float4 gv = ((const float4*)g)[threadIdx.x];
  const float4 bv = ((const float4*)b)[threadIdx.x];
  float xt[4];
  xt[0] = (xv.x - st.x) * st.y * gv.x + bv.x;
  xt[1] = (xv.y - st.x) * st.y * gv.y + bv.y;
  xt[2] = (xv.z - st.x) * st.y * gv.z + bv.z;
  xt[3] = (xv.w - st.x) * st.y * gv.w + bv.w;
  float acc[8] = {0, 0, 0, 0, 0, 0, 0, 0};
  const float* w = Wg + (size_t)(threadIdx.x << 2) * 8;
#pragma unroll
  for (int j = 0; j < 4; ++j)
#pragma unroll
    for (int e = 0; e < 8; ++e) acc[e] += xt[j] * w[j * 8 + e];
#pragma unroll
  for (int e = 0; e < 8; ++e) acc[e] = wave_sum(acc[e]);
  __shared__ float red[4][8];
  const int lane = threadIdx.x & 63, wave = threadIdx.x >> 6;
  if (lane == 0) {
#pragma unroll
    for (int e = 0; e < 8; ++e) red[wave][e] = acc[e];
  }
  __syncthreads();
  if (threadIdx.x < 8)
    logits[(size_t)row * 8 + threadIdx.x] = red[0][threadIdx.x] +
        red[1][threadIdx.x] + red[2][threadIdx.x] + red[3][threadIdx.x];
}

__global__ void top2_k(const float* __restrict__ logits, int* __restrict__ topi,
                       float* __restrict__ gatew, int* __restrict__ counts) {
  const int t = blockIdx.x * 256 + threadIdx.x;
  if (t >= 4096) return;
  float l[8];
#pragma unroll
  for (int e = 0; e < 8; ++e) l[e] = logits[(size_t)t * 8 + e];
  int i0 = 0;
  float v0 = l[0];
#pragma unroll
  for (int e = 1; e < 8; ++e)
    if (l[e] > v0) { v0 = l[e]; i0 = e; }
  int i1 = -1;
  float v1 = -1e30f;
#pragma unroll
  for (int e = 0; e < 8; ++e)
    if (e != i0 && l[e] > v1) { v1 = l[e]; i1 = e; }
  const float g0 = 1.0f / (1.0f + __expf(v1 - v0));
  topi[2 * t] = i0;
  topi[2 * t + 1] = i1;
  gatew[2 * t] = g0;
  gatew[2 * t + 1] = 1.0f - g0;
  atomicAdd(&counts[i0], 1);
  atomicAdd(&counts[i1], 1);
}

__global__ void offsets_k(const int* __restrict__ counts, int* __restrict__ offs,
                          int* __restrict__ cursors, int* __restrict__ blk_e,
                          int* __restrict__ blk_m, int* __restrict__ nblk) {
  if (threadIdx.x == 0) {
    int s = 0, nb = 0;
    for (int e = 0; e < 8; ++e) {
      offs[e] = s;
      for (int mb = 0; mb < counts[e]; mb += 128) {
        blk_e[nb] = e;
        blk_m[nb] = mb;
        ++nb;
      }
      s += counts[e];
    }
    *nblk = nb;
  }
  if (threadIdx.x < 8) cursors[threadIdx.x] = 0;
}

__global__ void route_k(const int* __restrict__ topi,
                        const int* __restrict__ offs, int* __restrict__ cursors,
                        int* __restrict__ token_ids, int* __restrict__ tok2slot) {
  const int i = blockIdx.x * 256 + threadIdx.x;
  if (i >= 8192) return;
  const int t = i >> 1;
  const int e = topi[i];
  const int pos = offs[e] + atomicAdd(&cursors[e], 1);
  token_ids[pos] = t;
  tok2slot[i] = pos;
}

__global__ void gather_k(const u16* __restrict__ X,
                         const int* __restrict__ token_ids,
                         u16* __restrict__ Xg) {
  const int i = blockIdx.x * 256 + threadIdx.x;
  const int slot = i >> 7, c = i & 127;
  ((uint4*)Xg)[(size_t)slot * 128 + c] =
      ((const uint4*)X)[(size_t)token_ids[slot] * 128 + c];
}

// out = x2 + sum_k g_k*(Yp0[s_k]+Yp1[s_k]+b2[e_k])
__global__ void combine_k(const float* __restrict__ X2,
                          const int* __restrict__ topi,
                          const float* __restrict__ gatew,
                          const int* __restrict__ tok2slot,
                          const float* __restrict__ Yp0,
                          const float* __restrict__ Yp1,
                          const float* __restrict__ b2,
                          float* __restrict__ Out) {
  const int t = blockIdx.x;
  const int c = threadIdx.x;
  float4 v = ((const float4*)(X2 + (size_t)t * 1024))[c];
  const int e0 = topi[2 * t], e1 = topi[2 * t + 1];
  const float g0 = gatew[2 * t], g1 = gatew[2 * t + 1];
  const int s0 = tok2slot[2 * t], s1 = tok2slot[2 * t + 1];
  const float4 ya0 = ((const float4*)(Yp0 + (size_t)s0 * 1024))[c];
  const float4 yb0 = ((const float4*)(Yp1 + (size_t)s0 * 1024))[c];
  const float4 ya1 = ((const float4*)(Yp0 + (size_t)s1 * 1024))[c];
  const float4 yb1 = ((const float4*)(Yp1 + (size_t)s1 * 1024))[c];
  const float4 c0 = ((const float4*)(b2 + (size_t)e0 * 1024))[c];
  const float4 c1 = ((const float4*)(b2 + (size_t)e1 * 1024))[c];
  v.x += g0 * (ya0.x + yb0.x + c0.x) + g1 * (ya1.x + yb1.x + c1.x);
  v.y += g0 * (ya0.y + yb0.y + c0.y) + g1 * (ya1.y + yb1.y + c1.y);
  v.z += g0 * (ya0.z + yb0.z + c0.z) + g1 * (ya1.z + yb1.z + c1.z);
  v.w += g0 * (ya0.w + yb0.w + c0.w) + g1 * (ya1.w + yb1.w + c1.w);
  ((float4*)(Out + (size_t)t * 1024))[c] = v;
}

__global__ void cvt_k(const float* __restrict__ in, u16* __restrict__ out, int n4) {
  const int i = blockIdx.x * 256 + threadIdx.x;
  if (i >= n4) return;
  const float4 v = ((const float4*)in)[i];
  ushort4 o;
  o.x = f2b(v.x);
  o.y = f2b(v.y);
  o.z = f2b(v.z);
  o.w = f2b(v.w);
  ((ushort4*)out)[i] = o;
}

__global__ __launch_bounds__(256) void transpose_cvt_k(
    const float* __restrict__ in, u16* __restrict__ out, int R, int C) {
  __shared__ float tile[32][33];
  const size_t eo = (size_t)blockIdx.z * (size_t)R * C;
  in += eo;
  out += eo;
  const int cb = blockIdx.x << 5, rb = blockIdx.y << 5;
  const int tx = threadIdx.x & 31, ty = threadIdx.x >> 5;
#pragma unroll
  for (int i = 0; i < 4; ++i)
    tile[ty + i * 8][tx] = in[(size_t)(rb + ty + i * 8) * C + cb + tx];
  __syncthreads();
#pragma unroll
  for (int i = 0; i < 4; ++i)
    out[(size_t)(cb + ty + i * 8) * R + rb + tx] = f2b(tile[tx][ty + i * 8]);
}

// V columns of qkv [T,3072] -> Vt[bh][64,2048] bf16
__global__ __launch_bounds__(256) void vtrans_k(const u16* __restrict__ qkv,
                                                u16* __restrict__ Vt) {
  __shared__ u16 tile[32][33];
  const int z = blockIdx.z, b = z >> 4, h = z & 15;
  const int sb = blockIdx.x << 5;
  const int db = blockIdx.y << 5;
  const int tx = threadIdx.x & 31, ty = threadIdx.x >> 5;
  const u16* src = qkv + ((size_t)b * 2048) * 3072 + 2048 + h * 64;
#pragma unroll
  for (int i = 0; i < 4; ++i)
    tile[ty + i * 8][tx] = src[(size_t)(sb + ty + i * 8) * 3072 + db + tx];
  __syncthreads();
  u16* dst = Vt + ((size_t)z * 64 + db) * 2048 + sb;
#pragma unroll
  for (int i = 0; i < 4; ++i)
    dst[(size_t)(ty + i * 8) * 2048 + tx] = tile[tx][ty + i * 8];
}

__global__ void zero_k(int* __restrict__ counts) {
  if (threadIdx.x < 8) counts[threadIdx.x] = 0;
}

extern "C" void kernel_launch(void* const* d_in, const int* in_sizes, int n_in,
                              void* d_out, int out_size, void* d_ws,
                              size_t ws_size, hipStream_t stream) {
  (void)in_sizes; (void)n_in; (void)out_size;
  const float* x = (const float*)d_in[0];
  const float* ln1_g = (const float*)d_in[1];
  const float* ln1_b = (const float*)d_in[2];
  const float* qkv_w = (const float*)d_in[3];
  const float* qkv_b = (const float*)d_in[4];
  const float* out_w = (const float*)d_in[5];
  const float* out_b = (const float*)d_in[6];
  const float* ln2_g = (const float*)d_in[7];
  const float* ln2_b = (const float*)d_in[8];
  const float* Wg = (const float*)d_in[9];
  const float* W1 = (const float*)d_in[10];
  const float* b1 = (const float*)d_in[11];
  const float* W2 = (const float*)d_in[12];
  const float* b2 = (const float*)d_in[13];
  float* out = (float*)d_out;

  const int T = 4096, H = 1024, F = 4096, E = 8;

  char* p = (char*)d_ws;
  auto alloc = [&](size_t n) {
    char* r = p;
    p += (n + 255) & ~(size_t)255;
    return r;
  };
  u16* qkvw_bf = (u16*)alloc((size_t)3 * H * H * 2);
  u16* outw_bf = (u16*)alloc((size_t)H * H * 2);
  u16* W1t = (u16*)alloc((size_t)E * F * H * 2);
  u16* W2t = (u16*)alloc((size_t)E * H * F * 2);
  u16* h1bf = (u16*)alloc((size_t)T * H * 2);    // dead after flash -> Yp1 lo
  u16* qkvbf = (u16*)alloc((size_t)T * 3 * H * 2);  // dead after flash -> Yp1 hi
  u16* obf = (u16*)alloc((size_t)T * H * 2);     // reused as h2bf
  float* x2 = (float*)alloc((size_t)T * H * 4);
  u16* H1 = (u16*)alloc((size_t)(2 * T + 128) * F * 2);  // pre-moe: out-proj partials
  float* Yp0 = (float*)alloc((size_t)2 * T * H * 4);
  u16* Xg = (u16*)alloc((size_t)(2 * T + 128) * H * 2);
  float* logits = (float*)alloc((size_t)T * E * 4);
  float2* stats = (float2*)alloc((size_t)T * 8);
  int* topi = (int*)alloc((size_t)T * 2 * 4);
  float* gatew = (float*)alloc((size_t)T * 2 * 4);
  int* counts = (int*)alloc(64);
  int* offs = (int*)alloc(64);
  int* cursors = (int*)alloc(64);
  int* blk_e = (int*)alloc(512);
  int* blk_m = (int*)alloc(512);
  int* nblk = (int*)alloc(64);
  int* token_ids = (int*)alloc((size_t)(2 * T + 128) * 4);
  int* tok2slot = (int*)alloc((size_t)2 * T * 4);
  if ((size_t)(p - (char*)d_ws) > ws_size) return;

  u16* Vt = h1bf;
  u16* h2bf = obf;
  float* Yp1 = (float*)h1bf;   // 32 MB contiguous (h1bf 8MB + qkvbf 24MB), dead after flash
  float* Po = (float*)H1;      // out-proj split-K partials (32 MB of H1's 64)

  zero_k<<<1, 64, 0, stream>>>(counts);
  cvt_k<<<3 * H * H / 4 / 256, 256, 0, stream>>>(qkv_w, qkvw_bf, 3 * H * H / 4);
  cvt_k<<<H * H / 4 / 256, 256, 0, stream>>>(out_w, outw_bf, H * H / 4);
  transpose_cvt_k<<<dim3(F / 32, H / 32, E), 256, 0, stream>>>(W1, W1t, H, F);
  transpose_cvt_k<<<dim3(H / 32, F / 32, E), 256, 0, stream>>>(W2, W2t, F, H);

  ln_k<<<T, 256, 0, stream>>>(x, ln1_g, ln1_b, h1bf, nullptr);

  gemm_k<4, 4><<<dim3(3 * H / 128, T / 128), 256, 0, stream>>>(
      h1bf, H, qkvw_bf, H, qkv_b, qkvbf, 3 * H, H);

  vtrans_k<<<dim3(2048 / 32, 2, 32), 256, 0, stream>>>(qkvbf, Vt);

  flash_attn_k<<<dim3(2048 / 64, 32), 256, 0, stream>>>(qkvbf, Vt, obf);

  // out proj, split-K=2 -> Po partials (H1 space), then reduce (+bias+resid)
  gemm_pk_k<4, 4><<<dim3(H / 128, T / 128, 2), 256, 0, stream>>>(
      obf, H, outw_bf, H, Po, T, H, 512);
  reduce2_k<<<T, 256, 0, stream>>>(Po, Po + (size_t)T * H, out_b, x, x2);

  ln_k<<<T, 256, 0, stream>>>(x2, ln2_g, ln2_b, h2bf, stats);
  logits_k<<<T, 256, 0, stream>>>(x2, stats, ln2_g, ln2_b, Wg, logits);
  top2_k<<<T / 256, 256, 0, stream>>>(logits, topi, gatew, counts);
  offsets_k<<<1, 64, 0, stream>>>(counts, offs, cursors, blk_e, blk_m, nblk);
  route_k<<<2 * T / 256, 256, 0, stream>>>(topi, offs, cursors, token_ids,
                                           tok2slot);
  gather_k<<<2 * T * (H / 8) / 256, 256, 0, stream>>>(h2bf, token_ids, Xg);

  moe_gemm1_k<<<dim3(F / 128, 72), 256, 0, stream>>>(Xg, W1t, b1, counts, offs,
                                                     blk_e, blk_m, nblk, H1);
  moe_gemm2_k<<<dim3(H / 128, 72, 2), 256, 0, stream>>>(H1, W2t, counts, offs,
                                                        blk_e, blk_m, nblk,
                                                        Yp0, Yp1);

  combine_k<<<T, 256, 0, stream>>>(x2, topi, gatew, tok2slot, Yp0, Yp1, b2, out);
}